// Round 22
// baseline (207.859 us; speedup 1.0000x reference)
//
#include <hip/hip_runtime.h>
#include <math.h>

// ---------------- constants ----------------
#define BIGV      1e9f
#define WARP_PEN  134.4f
#define MASK_INF_C 100000.0f

#define B   8
#define H   192
#define T   400
#define NP  401                  // padded matrix dim (0..400)
#define NPROB 16                 // 2 dirs x 8 batches
#define TSLAB 166464             // diag-staged D floats per problem (2601 tiles x 64)
#define SBLOCKS 768              // scalar-loss blocks
#define KLBLOCKS (49 * NPROB)    // 784 kl_gemm blocks

typedef float f32x4 __attribute__((ext_vector_type(4)));

// ---------------- workspace layout (float offsets) ----------------
#define SLOT_OFF 16
#define CNT_OFF 128              // 16 uint32 ready-counters (zeroed by memset)
#define LSP_OFF 160
#define LSQ_OFF (160 + B*T)
#define C1P_OFF (160 + 2*B*T)
#define C1Q_OFF (160 + 3*B*T)
#define DMAT_OFF (160 + 4*B*T)   // 12960 floats, 16B aligned

// Diagonal-staged tile layout (verified R16/R17).
__device__ __forceinline__ int diag_len(int s) { return (s <= 50) ? s + 1 : 101 - s; }
__device__ __forceinline__ int diag_i0 (int s) { return (s <= 50) ? 0 : s - 50; }
__device__ __forceinline__ int diag_Cs (int s) {
    return (s <= 51) ? s * (s + 1) / 2 : 2601 - (101 - s) * (102 - s) / 2;
}

// DPP wave_shr:1 — lane i gets src from lane i-1; lane 0 gets `fill`.
__device__ __forceinline__ float wave_shr1(float src, float fill) {
    int r = __builtin_amdgcn_update_dpp(__float_as_int(fill), __float_as_int(src),
                                        0x138 /*wave_shr:1*/, 0xf, 0xf, false);
    return __int_as_float(r);
}

// ---------------- kernel 2: per-(b,t) column sums (4-way h-split) ----------
__global__ __launch_bounds__(256)
void colsum(const float* __restrict__ logs_p, const float* __restrict__ m_p,
            const float* __restrict__ logs_q, const float* __restrict__ m_q,
            float* __restrict__ ws) {
    int b = blockIdx.x / 7;
    int lane = threadIdx.x & 63;
    int hq = threadIdx.x >> 6;                 // 0..3, 48 h each
    int t = (blockIdx.x % 7) * 64 + lane;
    __shared__ float part[4][4][64];
    float lp_s = 0.f, lq_s = 0.f, c1p = 0.f, c1q = 0.f;
    if (t < T) {
        int base = b*H*T + hq*48*T + t;
        const float* LP = logs_p + base;
        const float* MP = m_p   + base;
        const float* LQ = logs_q + base;
        const float* MQ = m_q   + base;
#pragma unroll 4
        for (int h = 0; h < 48; ++h) {
            float lp = LP[h*T], mp = MP[h*T];
            float lq = LQ[h*T], mq = MQ[h*T];
            lp_s += lp;
            lq_s += lq;
            c1p += __expf(-2.f*lp) * mp * mp;
            c1q += __expf(-2.f*lq) * mq * mq;
        }
    }
    part[hq][0][lane] = lp_s;
    part[hq][1][lane] = lq_s;
    part[hq][2][lane] = c1p;
    part[hq][3][lane] = c1q;
    __syncthreads();
    if (hq == 0 && t < T) {
        float a0 = part[0][0][lane] + part[1][0][lane] + part[2][0][lane] + part[3][0][lane];
        float a1 = part[0][1][lane] + part[1][1][lane] + part[2][1][lane] + part[3][1][lane];
        float a2 = part[0][2][lane] + part[1][2][lane] + part[2][2][lane] + part[3][2][lane];
        float a3 = part[0][3][lane] + part[1][3][lane] + part[2][3][lane] + part[3][3][lane];
        ws[LSP_OFF + b*T + t] = a0;
        ws[LSQ_OFF + b*T + t] = a1;
        ws[C1P_OFF + b*T + t] = a2;
        ws[C1Q_OFF + b*T + t] = a3;
    }
}

// ------- mega-fused kernel: DTW (blocks 0..15, spin on per-problem flag) ----
// ------- + KL GEMM (16..799, signals flag) + scalar losses (800..1567) -----
#define TILE 64
#define KH 32
__global__ __launch_bounds__(256)
void mega_fused(const float* __restrict__ z_p, const float* __restrict__ m_p,
                const float* __restrict__ logs_p,
                const float* __restrict__ z_q, const float* __restrict__ m_q,
                const float* __restrict__ logs_q,
                const int* __restrict__ p_mask, const int* __restrict__ z_mask,
                float* __restrict__ ws,
                const float* __restrict__ mel, const float* __restrict__ melh,
                const float* __restrict__ sg,  const float* __restrict__ se,
                const float* __restrict__ fr,  const float* __restrict__ ff) {
    __shared__ __align__(16) float As [KH][TILE+4];
    __shared__ __align__(16) float AMs[KH][TILE+4];
    __shared__ __align__(16) float Zs [KH][TILE+4];
    __shared__ __align__(16) float Z2s[KH][TILE+4];
    __shared__ float red[4][8];
    unsigned* cnt = (unsigned*)(ws + CNT_OFF);

    if (blockIdx.x < NPROB) {
        // ---------------- DTW path (consumer) ----------------
        if (threadIdx.x >= 64) return;   // no __syncthreads below this point
        int prob = blockIdx.x;
        int lane = threadIdx.x;
        const float* Dp = ws + DMAT_OFF + (size_t)prob * TSLAB;

        // wait until this problem's 49 kl blocks have signaled (ACQUIRE ->
        // L1/L2 invalidated so D reads below see L3-visible data)
        while (__hip_atomic_load(&cnt[prob], __ATOMIC_ACQUIRE,
                                 __HIP_MEMORY_SCOPE_AGENT) < 49u)
            __builtin_amdgcn_s_sleep(8);

        // persistent per-lane state
        float brow[8], browW[8], rightraw[8], rightW[8];
        float brold = BIGV, v00 = BIGV;
#pragma unroll
        for (int t = 0; t < 8; ++t) {
            brow[t] = BIGV; browW[t] = BIGV; rightraw[t] = BIGV; rightW[t] = BIGV;
        }

        f32x4 bufA[16], bufB[16], bufC[16];

        auto load_diag = [&](int sp, f32x4* buf) {
            if (sp > 100) sp = 100;
            int len = diag_len(sp), i0 = diag_i0(sp), Cs = diag_Cs(sp);
            int pos = lane - i0;
            pos = pos < 0 ? 0 : pos;
            pos = pos > len - 1 ? len - 1 : pos;
            const float* srcb = Dp + Cs*64 + pos*4;
            int str = len * 4;
#pragma unroll
            for (int k = 0; k < 16; ++k)
                buf[k] = *(const f32x4*)(srcb + k*str);
        };

#define TILE_STEP(CUR, NXT, SVAL, DO_LOAD)                                    \
    {                                                                          \
        const int s_ = (SVAL);                                                 \
        if (DO_LOAD) {                                                         \
            load_diag(s_ + 2, NXT);                                            \
            __builtin_amdgcn_sched_barrier(0);                                 \
        }                                                                      \
        bool jz = (s_ == lane);                                                \
        float brnew = brow[7];                                                 \
        _Pragma("unroll")                                                      \
        for (int c = 0; c < 8; ++c) {                                          \
            brow[c] = wave_shr1(brow[c], BIGV);                                \
            browW[c] = brow[c] + WARP_PEN;                                     \
        }                                                                      \
        float corner = wave_shr1(brold, BIGV);                                 \
        if (jz) corner = (lane == 0) ? 0.f : BIGV;                             \
        float dprev = corner;                                                  \
        _Pragma("unroll")                                                      \
        for (int r = 0; r < 8; ++r) {                                          \
            float leftW = jz ? BIGV : rightW[r];                               \
            float dnextrow = jz ? BIGV : rightraw[r];                          \
            float diag = dprev;                                                \
            _Pragma("unroll")                                                  \
            for (int ch = 0; ch < 2; ++ch) {                                   \
                f32x4 dvv = CUR[r*2 + ch];                                     \
                _Pragma("unroll")                                              \
                for (int cc = 0; cc < 4; ++cc) {                               \
                    const int c = ch*4 + cc;                                   \
                    float v = fminf(fminf(diag, browW[c]), leftW) + dvv[cc];   \
                    if (r == 0 && c == 0) v00 = v;                             \
                    float t_ = brow[c];                                        \
                    brow[c] = v;                                               \
                    float vW = v + WARP_PEN;                                   \
                    browW[c] = vW;                                             \
                    leftW = vW;                                                \
                    diag = t_;                                                 \
                }                                                              \
            }                                                                  \
            rightraw[r] = brow[7];                                             \
            rightW[r]   = browW[7];                                            \
            dprev = dnextrow;                                                  \
        }                                                                      \
        brold = brnew;                                                         \
    }

        load_diag(0, bufA);
        load_diag(1, bufB);

        for (int sb = 0; sb < 99; sb += 3) {
            TILE_STEP(bufA, bufC, sb,     1)
            TILE_STEP(bufB, bufA, sb + 1, 1)
            TILE_STEP(bufC, bufB, sb + 2, 1)
        }
        TILE_STEP(bufA, bufC, 99,  0)
        TILE_STEP(bufB, bufC, 100, 0)
#undef TILE_STEP

        if (lane == 50) atomicAdd(&ws[6 + (prob >> 3)], v00);
    } else if (blockIdx.x < NPROB + KLBLOCKS) {
        // ---------------- kl_gemm path (producer) ----------------
        int kbx  = blockIdx.x - NPROB;
        int prob = kbx / 49;
        int bx   = kbx % 49;
        int dir = prob >> 3, b = prob & 7;
        int tp = bx / 7, tq = bx % 7;
        int p0 = tp * TILE, q0 = tq * TILE;

        const float* lp_arr = dir ? logs_q : logs_p;
        const float* m_arr  = dir ? m_q    : m_p;
        const float* z_arr  = dir ? z_q    : z_p;
        const float* Lp = ws + (dir ? LSQ_OFF : LSP_OFF) + b*T;
        const float* Lq = ws + (dir ? LSP_OFF : LSQ_OFF) + b*T;
        const float* C1 = ws + (dir ? C1Q_OFF : C1P_OFF) + b*T;
        const int* rmask = dir ? z_mask : p_mask;
        const int* cmask = dir ? p_mask : z_mask;

        int tid = threadIdx.x;
        int tx = tid & 15, ty = tid >> 4;

        float acc1[4][4] = {{0.f}}, acc2[4][4] = {{0.f}};

        const float* lpB = lp_arr + b*H*T;
        const float* mB  = m_arr  + b*H*T;
        const float* zB  = z_arr  + b*H*T;

        for (int h0 = 0; h0 < H; h0 += KH) {
            for (int e = tid; e < KH*TILE; e += 256) {
                int hh = e >> 6, tt = e & 63;
                int pg = p0 + tt; if (pg > T-1) pg = T-1;
                int qg = q0 + tt; if (qg > T-1) qg = T-1;
                float lp = lpB[(h0+hh)*T + pg];
                float mv = mB [(h0+hh)*T + pg];
                float a  = __expf(-2.f*lp);
                As [hh][tt] = a;
                AMs[hh][tt] = a * mv;
                float zv = zB[(h0+hh)*T + qg];
                Zs [hh][tt] = zv;
                Z2s[hh][tt] = zv * zv;
            }
            __syncthreads();
#pragma unroll 8
            for (int hh = 0; hh < KH; ++hh) {
                const float4 av  = *(const float4*)(&As [hh][ty*4]);
                const float4 amv = *(const float4*)(&AMs[hh][ty*4]);
                const float4 zv  = *(const float4*)(&Zs [hh][tx*4]);
                const float4 z2v = *(const float4*)(&Z2s[hh][tx*4]);
                const float pa[4]  = {av.x, av.y, av.z, av.w};
                const float pam[4] = {amv.x, amv.y, amv.z, amv.w};
                const float qz[4]  = {zv.x, zv.y, zv.z, zv.w};
                const float qz2[4] = {z2v.x, z2v.y, z2v.z, z2v.w};
#pragma unroll
                for (int ii = 0; ii < 4; ++ii)
#pragma unroll
                    for (int jj = 0; jj < 4; ++jj) {
                        acc1[ii][jj] = fmaf(pa[ii],  qz2[jj], acc1[ii][jj]);
                        acc2[ii][jj] = fmaf(pam[ii], qz[jj],  acc2[ii][jj]);
                    }
            }
            __syncthreads();
        }

        float* Dm = ws + DMAT_OFF + (size_t)prob * TSLAB;
#pragma unroll
        for (int ii = 0; ii < 4; ++ii) {
            int p = p0 + ty*4 + ii;
            if (p <= NP-1) {
                int pc = p < T ? p : T-1;
                float lpv = Lp[pc];
                float c1v = C1[pc];
                bool pmv = (p < T) && (rmask[b*T + p] != 0);
#pragma unroll
                for (int jj = 0; jj < 4; ++jj) {
                    int q = q0 + tx*4 + jj;
                    if (q > NP-1) continue;
                    int qc = q < T ? q : T-1;
                    bool qmv = (q < T) && (cmask[b*T + q] != 0);
                    float val = lpv - Lq[qc] - 0.5f*(float)H
                              + 0.5f*(acc1[ii][jj] - 2.f*acc2[ii][jj] + c1v);
                    float outv = (pmv != qmv) ? MASK_INF_C : ((!pmv && !qmv) ? 0.f : val);
                    int I8 = p >> 3, J8 = q >> 3, sdg = I8 + J8;
                    int len = diag_len(sdg), i0 = diag_i0(sdg), Cs = diag_Cs(sdg);
                    int k = (p & 7) * 2 + ((q & 7) >> 2);
                    int off = Cs*64 + (k*len + (I8 - i0))*4 + (q & 3);
                    Dm[off] = outv;
                }
            }
        }
        // all D stores drained by the vmcnt(0) the compiler emits before
        // s_barrier; RELEASE/AGENT writes back L2 -> visible cross-XCD
        __syncthreads();
        if (threadIdx.x == 0)
            __hip_atomic_fetch_add(&cnt[prob], 1u, __ATOMIC_RELEASE,
                                   __HIP_MEMORY_SCOPE_AGENT);
    } else {
        // ---------------- scalar losses path ----------------
        float s0 = 0.f, s1 = 0.f, s2 = 0.f, s3 = 0.f, s4 = 0.f, s5 = 0.f;
        int tid = (blockIdx.x - NPROB - KLBLOCKS) * 256 + threadIdx.x;
        const int stride = SBLOCKS * 256;

        const float4* fr4 = (const float4*)fr;
        const float4* ff4 = (const float4*)ff;
        for (int i = tid; i < 3072000; i += stride) {
            float4 a = fr4[i], b = ff4[i];
            s2 += fabsf(a.x - b.x) + fabsf(a.y - b.y) + fabsf(a.z - b.z) + fabsf(a.w - b.w);
        }
        const float4* m4 = (const float4*)mel;
        const float4* mh4 = (const float4*)melh;
        for (int i = tid; i < 64000; i += stride) {
            float4 a = m4[i], b = mh4[i];
            s3 += fabsf(a.x - b.x) + fabsf(a.y - b.y) + fabsf(a.z - b.z) + fabsf(a.w - b.w);
        }
        const float4* g4 = (const float4*)sg;
        const float4* e4 = (const float4*)se;
        for (int i = tid; i < 4800; i += stride) {
            float4 a = g4[i], b = e4[i];
            float gx = 1.f - a.x, gy = 1.f - a.y, gz = 1.f - a.z, gw = 1.f - a.w;
            s0 += gx*gx + gy*gy + gz*gz + gw*gw;
            float hx = 1.f - b.x, hy = 1.f - b.y, hz = 1.f - b.z, hw = 1.f - b.w;
            s1 += hx*hx + hy*hy + hz*hz + hw*hw;
        }
        for (int i = tid; i < B*T; i += stride) {
            s4 += (float)p_mask[i];
            s5 += (float)z_mask[i];
        }
        for (int off = 32; off > 0; off >>= 1) {
            s0 += __shfl_down(s0, off); s1 += __shfl_down(s1, off);
            s2 += __shfl_down(s2, off); s3 += __shfl_down(s3, off);
            s4 += __shfl_down(s4, off); s5 += __shfl_down(s5, off);
        }
        int wid = threadIdx.x >> 6;
        if ((threadIdx.x & 63) == 0) {
            red[wid][0] = s0; red[wid][1] = s1; red[wid][2] = s2;
            red[wid][3] = s3; red[wid][4] = s4; red[wid][5] = s5;
        }
        __syncthreads();
        if (threadIdx.x == 0) {
            float t0 = 0.f, t1 = 0.f, t2 = 0.f, t3 = 0.f, t4 = 0.f, t5 = 0.f;
#pragma unroll
            for (int w = 0; w < 4; ++w) {
                t0 += red[w][0]; t1 += red[w][1]; t2 += red[w][2];
                t3 += red[w][3]; t4 += red[w][4]; t5 += red[w][5];
            }
            float* slot = ws + SLOT_OFF + (blockIdx.x & 7) * 16;
            atomicAdd(&slot[0], t0); atomicAdd(&slot[1], t1);
            atomicAdd(&slot[2], t2); atomicAdd(&slot[3], t3);
            atomicAdd(&slot[4], t4); atomicAdd(&slot[5], t5);
        }
    }
}

// ---------------- kernel 5: assemble outputs ----------------
__global__ void finalize(const float* __restrict__ acc,
                         const float* __restrict__ dur,
                         const float* __restrict__ pit,
                         float* __restrict__ out) {
    if (threadIdx.x != 0 || blockIdx.x != 0) return;
    float t[6] = {0.f, 0.f, 0.f, 0.f, 0.f, 0.f};
    for (int s = 0; s < 8; ++s)
        for (int c = 0; c < 6; ++c)
            t[c] += acc[SLOT_OFF + s*16 + c];
    float gen  = t[0] / 3200.f;
    float e2e  = t[1] / 3200.f;
    float fm   = 4.f * t[2] / 409600.f;
    float melv = 45.f * t[3] / 256000.f;
    float d    = dur[0];
    float p    = pit[0];
    float kl   = acc[6] / t[4];
    float klf  = acc[7] / t[5];
    out[0] = gen; out[1] = e2e; out[2] = fm; out[3] = melv;
    out[4] = d;   out[5] = p;   out[6] = kl; out[7] = klf;
    out[8] = gen + e2e + fm + melv + d + p + kl + klf;
}

// ---------------- launch ----------------
extern "C" void kernel_launch(void* const* d_in, const int* in_sizes, int n_in,
                              void* d_out, int out_size, void* d_ws, size_t ws_size,
                              hipStream_t stream) {
    const float* mel    = (const float*)d_in[0];
    const float* melh   = (const float*)d_in[1];
    const float* sg     = (const float*)d_in[2];
    const float* se     = (const float*)d_in[3];
    const float* fr     = (const float*)d_in[4];
    const float* ff     = (const float*)d_in[5];
    const float* dur    = (const float*)d_in[6];
    const float* pit    = (const float*)d_in[7];
    const float* z_p    = (const float*)d_in[8];
    const float* m_p    = (const float*)d_in[9];
    const float* logs_p = (const float*)d_in[10];
    const float* z_q    = (const float*)d_in[11];
    const float* m_q    = (const float*)d_in[12];
    const float* logs_q = (const float*)d_in[13];
    const int*   p_mask = (const int*)d_in[14];
    const int*   z_mask = (const int*)d_in[15];
    float* ws  = (float*)d_ws;
    float* out = (float*)d_out;

    hipMemsetAsync(ws, 0, 160 * sizeof(float), stream);
    colsum<<<B*7, 256, 0, stream>>>(logs_p, m_p, logs_q, m_q, ws);
    mega_fused<<<NPROB + KLBLOCKS + SBLOCKS, 256, 0, stream>>>(
        z_p, m_p, logs_p, z_q, m_q, logs_q, p_mask, z_mask, ws,
        mel, melh, sg, se, fr, ff);
    finalize<<<1, 64, 0, stream>>>(ws, dur, pit, out);
}

// Round 23
// 180.138 us; speedup vs baseline: 1.1539x; 1.1539x over previous
//
#include <hip/hip_runtime.h>
#include <math.h>

// ---------------- constants ----------------
#define BIGV      1e9f
#define WARP_PEN  134.4f
#define MASK_INF_C 100000.0f

#define B   8
#define H   192
#define T   400
#define NP  401                  // padded matrix dim (0..400)
#define NPROB 16                 // 2 dirs x 8 batches
#define TSLAB 166464             // diag-staged D floats per problem (2601 tiles x 64)
#define SBLOCKS 768              // scalar-loss blocks
#define KL2BLOCKS (16 * NPROB)   // 256 kl blocks (128x128 tiles, 4x4 per problem)

typedef float f32x4 __attribute__((ext_vector_type(4)));

// ---------------- workspace layout (float offsets) ----------------
#define SLOT_OFF 16
#define LSP_OFF 160
#define LSQ_OFF (160 + B*T)
#define C1P_OFF (160 + 2*B*T)
#define C1Q_OFF (160 + 3*B*T)
#define DMAT_OFF (160 + 4*B*T)   // 12960 floats, 16B aligned

// Diagonal-staged tile layout (verified R16-R20).
__device__ __forceinline__ int diag_len(int s) { return (s <= 50) ? s + 1 : 101 - s; }
__device__ __forceinline__ int diag_i0 (int s) { return (s <= 50) ? 0 : s - 50; }
__device__ __forceinline__ int diag_Cs (int s) {
    return (s <= 51) ? s * (s + 1) / 2 : 2601 - (101 - s) * (102 - s) / 2;
}

// DPP wave_shr:1 — lane i gets src from lane i-1; lane 0 gets `fill`.
__device__ __forceinline__ float wave_shr1(float src, float fill) {
    int r = __builtin_amdgcn_update_dpp(__float_as_int(fill), __float_as_int(src),
                                        0x138 /*wave_shr:1*/, 0xf, 0xf, false);
    return __int_as_float(r);
}

// ---------------- kernel 2: per-(b,t) column sums (4-way h-split) ----------
__global__ __launch_bounds__(256)
void colsum(const float* __restrict__ logs_p, const float* __restrict__ m_p,
            const float* __restrict__ logs_q, const float* __restrict__ m_q,
            float* __restrict__ ws) {
    int b = blockIdx.x / 7;
    int lane = threadIdx.x & 63;
    int hq = threadIdx.x >> 6;                 // 0..3, 48 h each
    int t = (blockIdx.x % 7) * 64 + lane;
    __shared__ float part[4][4][64];
    float lp_s = 0.f, lq_s = 0.f, c1p = 0.f, c1q = 0.f;
    if (t < T) {
        int base = b*H*T + hq*48*T + t;
        const float* LP = logs_p + base;
        const float* MP = m_p   + base;
        const float* LQ = logs_q + base;
        const float* MQ = m_q   + base;
#pragma unroll 4
        for (int h = 0; h < 48; ++h) {
            float lp = LP[h*T], mp = MP[h*T];
            float lq = LQ[h*T], mq = MQ[h*T];
            lp_s += lp;
            lq_s += lq;
            c1p += __expf(-2.f*lp) * mp * mp;
            c1q += __expf(-2.f*lq) * mq * mq;
        }
    }
    part[hq][0][lane] = lp_s;
    part[hq][1][lane] = lq_s;
    part[hq][2][lane] = c1p;
    part[hq][3][lane] = c1q;
    __syncthreads();
    if (hq == 0 && t < T) {
        float a0 = part[0][0][lane] + part[1][0][lane] + part[2][0][lane] + part[3][0][lane];
        float a1 = part[0][1][lane] + part[1][1][lane] + part[2][1][lane] + part[3][1][lane];
        float a2 = part[0][2][lane] + part[1][2][lane] + part[2][2][lane] + part[3][2][lane];
        float a3 = part[0][3][lane] + part[1][3][lane] + part[2][3][lane] + part[3][3][lane];
        ws[LSP_OFF + b*T + t] = a0;
        ws[LSQ_OFF + b*T + t] = a1;
        ws[C1P_OFF + b*T + t] = a2;
        ws[C1Q_OFF + b*T + t] = a3;
    }
}

// ---------------- fused kernel: KL GEMM (blocks 0..255) + scalar losses ----
// 128x128 tile, 8x8 micro-tile as 2x2 quadrants of 4x4 (conflict-free b128
// reads), Z^2 computed in registers (no Z2s array). LDS reads per FMA cut
// ~2.6x vs the 64^2 kernel -> no longer LDS-BW-bound.
#define TILE 128
#define KH 16
__global__ __launch_bounds__(256)
void fused_kl_scalar(const float* __restrict__ z_p, const float* __restrict__ m_p,
                     const float* __restrict__ logs_p,
                     const float* __restrict__ z_q, const float* __restrict__ m_q,
                     const float* __restrict__ logs_q,
                     const int* __restrict__ p_mask, const int* __restrict__ z_mask,
                     float* __restrict__ ws,
                     const float* __restrict__ mel, const float* __restrict__ melh,
                     const float* __restrict__ sg,  const float* __restrict__ se,
                     const float* __restrict__ fr,  const float* __restrict__ ff) {
    __shared__ __align__(16) float As [KH][TILE+4];
    __shared__ __align__(16) float AMs[KH][TILE+4];
    __shared__ __align__(16) float Zs [KH][TILE+4];
    __shared__ float red[4][8];

    if (blockIdx.x < KL2BLOCKS) {
        // ---------------- kl_gemm path ----------------
        int prob = blockIdx.x >> 4;
        int tix  = blockIdx.x & 15;
        int dir = prob >> 3, b = prob & 7;
        int tp = tix >> 2, tq = tix & 3;
        int p0 = tp * TILE, q0 = tq * TILE;

        const float* lp_arr = dir ? logs_q : logs_p;
        const float* m_arr  = dir ? m_q    : m_p;
        const float* z_arr  = dir ? z_q    : z_p;
        const float* Lp = ws + (dir ? LSQ_OFF : LSP_OFF) + b*T;
        const float* Lq = ws + (dir ? LSP_OFF : LSQ_OFF) + b*T;
        const float* C1 = ws + (dir ? C1Q_OFF : C1P_OFF) + b*T;
        const int* rmask = dir ? z_mask : p_mask;
        const int* cmask = dir ? p_mask : z_mask;

        int tid = threadIdx.x;
        int tx = tid & 15, ty = tid >> 4;

        float acc1[2][2][4][4] = {{{{0.f}}}}, acc2[2][2][4][4] = {{{{0.f}}}};

        const float* lpB = lp_arr + b*H*T;
        const float* mB  = m_arr  + b*H*T;
        const float* zB  = z_arr  + b*H*T;

        for (int h0 = 0; h0 < H; h0 += KH) {
            for (int e = tid; e < KH*TILE; e += 256) {
                int hh = e >> 7, tt = e & 127;
                int pg = p0 + tt; if (pg > T-1) pg = T-1;
                int qg = q0 + tt; if (qg > T-1) qg = T-1;
                float lp = lpB[(h0+hh)*T + pg];
                float mv = mB [(h0+hh)*T + pg];
                float a  = __expf(-2.f*lp);
                As [hh][tt] = a;
                AMs[hh][tt] = a * mv;
                Zs [hh][tt] = zB[(h0+hh)*T + qg];
            }
            __syncthreads();
#pragma unroll 4
            for (int hh = 0; hh < KH; ++hh) {
                const float4 aLo  = *(const float4*)(&As [hh][ty*4]);
                const float4 aHi  = *(const float4*)(&As [hh][64 + ty*4]);
                const float4 amLo = *(const float4*)(&AMs[hh][ty*4]);
                const float4 amHi = *(const float4*)(&AMs[hh][64 + ty*4]);
                const float4 zLo  = *(const float4*)(&Zs [hh][tx*4]);
                const float4 zHi  = *(const float4*)(&Zs [hh][64 + tx*4]);
                const float aL[4]  = {aLo.x, aLo.y, aLo.z, aLo.w};
                const float aH[4]  = {aHi.x, aHi.y, aHi.z, aHi.w};
                const float amL[4] = {amLo.x, amLo.y, amLo.z, amLo.w};
                const float amH[4] = {amHi.x, amHi.y, amHi.z, amHi.w};
                const float zL[4]  = {zLo.x, zLo.y, zLo.z, zLo.w};
                const float zH[4]  = {zHi.x, zHi.y, zHi.z, zHi.w};
                float z2L[4], z2H[4];
#pragma unroll
                for (int j = 0; j < 4; ++j) { z2L[j] = zL[j]*zL[j]; z2H[j] = zH[j]*zH[j]; }
#pragma unroll
                for (int ii = 0; ii < 4; ++ii)
#pragma unroll
                    for (int jj = 0; jj < 4; ++jj) {
                        acc1[0][0][ii][jj] = fmaf(aL[ii],  z2L[jj], acc1[0][0][ii][jj]);
                        acc1[0][1][ii][jj] = fmaf(aL[ii],  z2H[jj], acc1[0][1][ii][jj]);
                        acc1[1][0][ii][jj] = fmaf(aH[ii],  z2L[jj], acc1[1][0][ii][jj]);
                        acc1[1][1][ii][jj] = fmaf(aH[ii],  z2H[jj], acc1[1][1][ii][jj]);
                        acc2[0][0][ii][jj] = fmaf(amL[ii], zL[jj],  acc2[0][0][ii][jj]);
                        acc2[0][1][ii][jj] = fmaf(amL[ii], zH[jj],  acc2[0][1][ii][jj]);
                        acc2[1][0][ii][jj] = fmaf(amH[ii], zL[jj],  acc2[1][0][ii][jj]);
                        acc2[1][1][ii][jj] = fmaf(amH[ii], zH[jj],  acc2[1][1][ii][jj]);
                    }
            }
            __syncthreads();
        }

        // epilogue: kl value + pad/mask, DIAG-STAGED write (verified R16)
        float* Dm = ws + DMAT_OFF + (size_t)prob * TSLAB;
#pragma unroll
        for (int up = 0; up < 2; ++up)
#pragma unroll
        for (int ii = 0; ii < 4; ++ii) {
            int p = p0 + up*64 + ty*4 + ii;
            if (p > NP-1) continue;
            int pc = p < T ? p : T-1;
            float lpv = Lp[pc];
            float c1v = C1[pc];
            bool pmv = (p < T) && (rmask[b*T + p] != 0);
#pragma unroll
            for (int uq = 0; uq < 2; ++uq)
#pragma unroll
            for (int jj = 0; jj < 4; ++jj) {
                int q = q0 + uq*64 + tx*4 + jj;
                if (q > NP-1) continue;
                int qc = q < T ? q : T-1;
                bool qmv = (q < T) && (cmask[b*T + q] != 0);
                float val = lpv - Lq[qc] - 0.5f*(float)H
                          + 0.5f*(acc1[up][uq][ii][jj] - 2.f*acc2[up][uq][ii][jj] + c1v);
                float outv = (pmv != qmv) ? MASK_INF_C : ((!pmv && !qmv) ? 0.f : val);
                int I8 = p >> 3, J8 = q >> 3, sdg = I8 + J8;
                int len = diag_len(sdg), i0 = diag_i0(sdg), Cs = diag_Cs(sdg);
                int k = (p & 7) * 2 + ((q & 7) >> 2);
                int off = Cs*64 + (k*len + (I8 - i0))*4 + (q & 3);
                Dm[off] = outv;
            }
        }
    } else {
        // ---------------- scalar losses path ----------------
        float s0 = 0.f, s1 = 0.f, s2 = 0.f, s3 = 0.f, s4 = 0.f, s5 = 0.f;
        int tid = (blockIdx.x - KL2BLOCKS) * 256 + threadIdx.x;
        const int stride = SBLOCKS * 256;

        const float4* fr4 = (const float4*)fr;
        const float4* ff4 = (const float4*)ff;
        for (int i = tid; i < 3072000; i += stride) {
            float4 a = fr4[i], b = ff4[i];
            s2 += fabsf(a.x - b.x) + fabsf(a.y - b.y) + fabsf(a.z - b.z) + fabsf(a.w - b.w);
        }
        const float4* m4 = (const float4*)mel;
        const float4* mh4 = (const float4*)melh;
        for (int i = tid; i < 64000; i += stride) {
            float4 a = m4[i], b = mh4[i];
            s3 += fabsf(a.x - b.x) + fabsf(a.y - b.y) + fabsf(a.z - b.z) + fabsf(a.w - b.w);
        }
        const float4* g4 = (const float4*)sg;
        const float4* e4 = (const float4*)se;
        for (int i = tid; i < 4800; i += stride) {
            float4 a = g4[i], b = e4[i];
            float gx = 1.f - a.x, gy = 1.f - a.y, gz = 1.f - a.z, gw = 1.f - a.w;
            s0 += gx*gx + gy*gy + gz*gz + gw*gw;
            float hx = 1.f - b.x, hy = 1.f - b.y, hz = 1.f - b.z, hw = 1.f - b.w;
            s1 += hx*hx + hy*hy + hz*hz + hw*hw;
        }
        for (int i = tid; i < B*T; i += stride) {
            s4 += (float)p_mask[i];
            s5 += (float)z_mask[i];
        }
        for (int off = 32; off > 0; off >>= 1) {
            s0 += __shfl_down(s0, off); s1 += __shfl_down(s1, off);
            s2 += __shfl_down(s2, off); s3 += __shfl_down(s3, off);
            s4 += __shfl_down(s4, off); s5 += __shfl_down(s5, off);
        }
        int wid = threadIdx.x >> 6;
        if ((threadIdx.x & 63) == 0) {
            red[wid][0] = s0; red[wid][1] = s1; red[wid][2] = s2;
            red[wid][3] = s3; red[wid][4] = s4; red[wid][5] = s5;
        }
        __syncthreads();
        if (threadIdx.x == 0) {
            float t0 = 0.f, t1 = 0.f, t2 = 0.f, t3 = 0.f, t4 = 0.f, t5 = 0.f;
#pragma unroll
            for (int w = 0; w < 4; ++w) {
                t0 += red[w][0]; t1 += red[w][1]; t2 += red[w][2];
                t3 += red[w][3]; t4 += red[w][4]; t5 += red[w][5];
            }
            float* slot = ws + SLOT_OFF + (blockIdx.x & 7) * 16;
            atomicAdd(&slot[0], t0); atomicAdd(&slot[1], t1);
            atomicAdd(&slot[2], t2); atomicAdd(&slot[3], t3);
            atomicAdd(&slot[4], t4); atomicAdd(&slot[5], t5);
        }
    }
}

// ---------------- kernel 4: DTW tile wavefront — STANDALONE ----------------
// 16 blocks x 64 threads, launch_bounds(64,1). NEW: tile computed along its
// 15 INTERNAL anti-diagonals (statically unrolled) — cells on a mini-diagonal
// are independent, so the old serial 64-cell chain (~1000cy of dependent
// latency per step, the stubborn residual) becomes ~15 dependent levels with
// up to 8-wide ILP.
__global__ __launch_bounds__(64, 1)
void dtw_diag(const float* __restrict__ Dd, float* __restrict__ acc) {
    int prob = blockIdx.x;
    int lane = threadIdx.x;
    const float* Dp = Dd + (size_t)prob * TSLAB;

    float brow[8];                      // raw bottom row of my tile
    float rightraw[8], rightW[8];       // my col-7 raw / +W
    float brold = BIGV, v00 = BIGV;
#pragma unroll
    for (int t = 0; t < 8; ++t) { brow[t] = BIGV; rightraw[t] = BIGV; rightW[t] = BIGV; }

    f32x4 bufA[16], bufB[16];

    auto load_diag = [&](int sp, f32x4* buf) {
        if (sp > 100) sp = 100;
        int len = diag_len(sp), i0 = diag_i0(sp), Cs = diag_Cs(sp);
        int pos = lane - i0;
        pos = pos < 0 ? 0 : pos;
        pos = pos > len - 1 ? len - 1 : pos;
        const float* srcb = Dp + Cs*64 + pos*4;
        int str = len * 4;
#pragma unroll
        for (int k = 0; k < 16; ++k)
            buf[k] = *(const f32x4*)(srcb + k*str);
    };

#define TILE_STEP(CUR, NXT, SVAL, DO_LOAD)                                    \
    {                                                                          \
        const int s_ = (SVAL);                                                 \
        if (DO_LOAD) {                                                         \
            load_diag(s_ + 1, NXT);                                            \
            __builtin_amdgcn_sched_barrier(0);                                 \
        }                                                                      \
        bool jz = (s_ == lane);            /* J == 0 */                        \
        float brnew = brow[7];                                                 \
        float upraw[8], upW[8];                                                \
        _Pragma("unroll")                                                      \
        for (int c = 0; c < 8; ++c) {                                          \
            upraw[c] = wave_shr1(brow[c], BIGV);                               \
            upW[c] = upraw[c] + WARP_PEN;                                      \
        }                                                                      \
        float corner = wave_shr1(brold, BIGV);                                 \
        if (jz) corner = (lane == 0) ? 0.f : BIGV;                             \
        float vr[8][8], vw[8][8];                                              \
        _Pragma("unroll")                                                      \
        for (int d = 0; d < 15; ++d) {                                         \
            _Pragma("unroll")                                                  \
            for (int r = 0; r < 8; ++r) {                                      \
                const int c = d - r;                                           \
                if (c < 0 || c > 7) continue;                                  \
                float uw = (r == 0) ? upW[c] : vw[r-1][c];                     \
                float lw = (c == 0) ? (jz ? BIGV : rightW[r]) : vw[r][c-1];    \
                float dg;                                                      \
                if (r == 0 && c == 0)      dg = corner;                        \
                else if (r == 0)           dg = upraw[c-1];                    \
                else if (c == 0)           dg = jz ? BIGV : rightraw[r-1];     \
                else                       dg = vr[r-1][c-1];                  \
                float v = fminf(fminf(uw, lw), dg) + CUR[r*2 + (c>>2)][c&3];   \
                vr[r][c] = v;                                                  \
                vw[r][c] = v + WARP_PEN;                                       \
            }                                                                  \
        }                                                                      \
        v00 = vr[0][0];                                                        \
        _Pragma("unroll")                                                      \
        for (int r = 0; r < 8; ++r) { rightraw[r] = vr[r][7]; rightW[r] = vw[r][7]; } \
        _Pragma("unroll")                                                      \
        for (int c = 0; c < 8; ++c) brow[c] = vr[7][c];                        \
        brold = brnew;                                                         \
    }

    load_diag(0, bufA);

    for (int sb = 0; sb < 100; sb += 2) {
        TILE_STEP(bufA, bufB, sb,     1)
        TILE_STEP(bufB, bufA, sb + 1, 1)
    }
    TILE_STEP(bufA, bufB, 100, 0)   // final tile-diagonal
#undef TILE_STEP

    // R[400][400] = tile(50,50) cell (0,0), computed at s=100 by lane 50
    if (lane == 50) atomicAdd(&acc[6 + (prob >> 3)], v00);
}

// ---------------- kernel 5: assemble outputs ----------------
__global__ void finalize(const float* __restrict__ acc,
                         const float* __restrict__ dur,
                         const float* __restrict__ pit,
                         float* __restrict__ out) {
    if (threadIdx.x != 0 || blockIdx.x != 0) return;
    float t[6] = {0.f, 0.f, 0.f, 0.f, 0.f, 0.f};
    for (int s = 0; s < 8; ++s)
        for (int c = 0; c < 6; ++c)
            t[c] += acc[SLOT_OFF + s*16 + c];
    float gen  = t[0] / 3200.f;
    float e2e  = t[1] / 3200.f;
    float fm   = 4.f * t[2] / 409600.f;
    float melv = 45.f * t[3] / 256000.f;
    float d    = dur[0];
    float p    = pit[0];
    float kl   = acc[6] / t[4];
    float klf  = acc[7] / t[5];
    out[0] = gen; out[1] = e2e; out[2] = fm; out[3] = melv;
    out[4] = d;   out[5] = p;   out[6] = kl; out[7] = klf;
    out[8] = gen + e2e + fm + melv + d + p + kl + klf;
}

// ---------------- launch ----------------
extern "C" void kernel_launch(void* const* d_in, const int* in_sizes, int n_in,
                              void* d_out, int out_size, void* d_ws, size_t ws_size,
                              hipStream_t stream) {
    const float* mel    = (const float*)d_in[0];
    const float* melh   = (const float*)d_in[1];
    const float* sg     = (const float*)d_in[2];
    const float* se     = (const float*)d_in[3];
    const float* fr     = (const float*)d_in[4];
    const float* ff     = (const float*)d_in[5];
    const float* dur    = (const float*)d_in[6];
    const float* pit    = (const float*)d_in[7];
    const float* z_p    = (const float*)d_in[8];
    const float* m_p    = (const float*)d_in[9];
    const float* logs_p = (const float*)d_in[10];
    const float* z_q    = (const float*)d_in[11];
    const float* m_q    = (const float*)d_in[12];
    const float* logs_q = (const float*)d_in[13];
    const int*   p_mask = (const int*)d_in[14];
    const int*   z_mask = (const int*)d_in[15];
    float* ws  = (float*)d_ws;
    float* out = (float*)d_out;

    hipMemsetAsync(ws, 0, 160 * sizeof(float), stream);
    colsum<<<B*7, 256, 0, stream>>>(logs_p, m_p, logs_q, m_q, ws);
    fused_kl_scalar<<<KL2BLOCKS + SBLOCKS, 256, 0, stream>>>(
        z_p, m_p, logs_p, z_q, m_q, logs_q, p_mask, z_mask, ws,
        mel, melh, sg, se, fr, ff);
    dtw_diag<<<NPROB, 64, 0, stream>>>(ws + DMAT_OFF, ws);
    finalize<<<1, 64, 0, stream>>>(ws, dur, pit, out);
}

// Round 24
// 155.583 us; speedup vs baseline: 1.3360x; 1.1578x over previous
//
#include <hip/hip_runtime.h>
#include <math.h>

// ---------------- constants ----------------
#define BIGV      1e9f
#define WARP_PEN  134.4f
#define MASK_INF_C 100000.0f

#define B   8
#define H   192
#define T   400
#define NP  401                  // padded matrix dim (0..400)
#define NPROB 16                 // 2 dirs x 8 batches
#define TSLAB 166464             // diag-staged D floats per problem (2601 tiles x 64)
#define SBLOCKS 768              // scalar-loss blocks
#define KLBLOCKS (49 * NPROB)    // 784 kl_gemm blocks (64x64 tiles)

typedef float f32x4 __attribute__((ext_vector_type(4)));

// ---------------- workspace layout (float offsets) ----------------
#define SLOT_OFF 16
#define LSP_OFF 160
#define LSQ_OFF (160 + B*T)
#define C1P_OFF (160 + 2*B*T)
#define C1Q_OFF (160 + 3*B*T)
#define DMAT_OFF (160 + 4*B*T)   // 12960 floats, 16B aligned

// Diagonal-staged tile layout (verified R16-R23).
__device__ __forceinline__ int diag_len(int s) { return (s <= 50) ? s + 1 : 101 - s; }
__device__ __forceinline__ int diag_i0 (int s) { return (s <= 50) ? 0 : s - 50; }
__device__ __forceinline__ int diag_Cs (int s) {
    return (s <= 51) ? s * (s + 1) / 2 : 2601 - (101 - s) * (102 - s) / 2;
}

// DPP wave_shr:1 — lane i gets src from lane i-1; lane 0 gets `fill`.
__device__ __forceinline__ float wave_shr1(float src, float fill) {
    int r = __builtin_amdgcn_update_dpp(__float_as_int(fill), __float_as_int(src),
                                        0x138 /*wave_shr:1*/, 0xf, 0xf, false);
    return __int_as_float(r);
}

// ---------------- kernel 2: per-(b,t) column sums (4-way h-split) ----------
__global__ __launch_bounds__(256)
void colsum(const float* __restrict__ logs_p, const float* __restrict__ m_p,
            const float* __restrict__ logs_q, const float* __restrict__ m_q,
            float* __restrict__ ws) {
    int b = blockIdx.x / 7;
    int lane = threadIdx.x & 63;
    int hq = threadIdx.x >> 6;                 // 0..3, 48 h each
    int t = (blockIdx.x % 7) * 64 + lane;
    __shared__ float part[4][4][64];
    float lp_s = 0.f, lq_s = 0.f, c1p = 0.f, c1q = 0.f;
    if (t < T) {
        int base = b*H*T + hq*48*T + t;
        const float* LP = logs_p + base;
        const float* MP = m_p   + base;
        const float* LQ = logs_q + base;
        const float* MQ = m_q   + base;
#pragma unroll 4
        for (int h = 0; h < 48; ++h) {
            float lp = LP[h*T], mp = MP[h*T];
            float lq = LQ[h*T], mq = MQ[h*T];
            lp_s += lp;
            lq_s += lq;
            c1p += __expf(-2.f*lp) * mp * mp;
            c1q += __expf(-2.f*lq) * mq * mq;
        }
    }
    part[hq][0][lane] = lp_s;
    part[hq][1][lane] = lq_s;
    part[hq][2][lane] = c1p;
    part[hq][3][lane] = c1q;
    __syncthreads();
    if (hq == 0 && t < T) {
        float a0 = part[0][0][lane] + part[1][0][lane] + part[2][0][lane] + part[3][0][lane];
        float a1 = part[0][1][lane] + part[1][1][lane] + part[2][1][lane] + part[3][1][lane];
        float a2 = part[0][2][lane] + part[1][2][lane] + part[2][2][lane] + part[3][2][lane];
        float a3 = part[0][3][lane] + part[1][3][lane] + part[2][3][lane] + part[3][3][lane];
        ws[LSP_OFF + b*T + t] = a0;
        ws[LSQ_OFF + b*T + t] = a1;
        ws[C1P_OFF + b*T + t] = a2;
        ws[C1Q_OFF + b*T + t] = a3;
    }
}

// ---------------- fused kernel: KL GEMM (blocks 0..783) + scalar losses ----
// 64x64 tile, KH=32 (R20's proven 70us config) MINUS the Z2s LDS array:
// z^2 computed in registers -> ds_read_b128 per hh drops 4->3 (kernel is
// LDS-port-bound: ~47us -> ~35us port time), LDS 35.3KB -> 27KB.
#define TILE 64
#define KH 32
__global__ __launch_bounds__(256)
void fused_kl_scalar(const float* __restrict__ z_p, const float* __restrict__ m_p,
                     const float* __restrict__ logs_p,
                     const float* __restrict__ z_q, const float* __restrict__ m_q,
                     const float* __restrict__ logs_q,
                     const int* __restrict__ p_mask, const int* __restrict__ z_mask,
                     float* __restrict__ ws,
                     const float* __restrict__ mel, const float* __restrict__ melh,
                     const float* __restrict__ sg,  const float* __restrict__ se,
                     const float* __restrict__ fr,  const float* __restrict__ ff) {
    __shared__ __align__(16) float As [KH][TILE+4];
    __shared__ __align__(16) float AMs[KH][TILE+4];
    __shared__ __align__(16) float Zs [KH][TILE+4];
    __shared__ float red[4][8];

    if (blockIdx.x < KLBLOCKS) {
        // ---------------- kl_gemm path ----------------
        int prob = blockIdx.x / 49;
        int bx   = blockIdx.x % 49;
        int dir = prob >> 3, b = prob & 7;
        int tp = bx / 7, tq = bx % 7;
        int p0 = tp * TILE, q0 = tq * TILE;

        const float* lp_arr = dir ? logs_q : logs_p;
        const float* m_arr  = dir ? m_q    : m_p;
        const float* z_arr  = dir ? z_q    : z_p;
        const float* Lp = ws + (dir ? LSQ_OFF : LSP_OFF) + b*T;
        const float* Lq = ws + (dir ? LSP_OFF : LSQ_OFF) + b*T;
        const float* C1 = ws + (dir ? C1Q_OFF : C1P_OFF) + b*T;
        const int* rmask = dir ? z_mask : p_mask;
        const int* cmask = dir ? p_mask : z_mask;

        int tid = threadIdx.x;
        int tx = tid & 15, ty = tid >> 4;

        float acc1[4][4] = {{0.f}}, acc2[4][4] = {{0.f}};

        const float* lpB = lp_arr + b*H*T;
        const float* mB  = m_arr  + b*H*T;
        const float* zB  = z_arr  + b*H*T;

        for (int h0 = 0; h0 < H; h0 += KH) {
            for (int e = tid; e < KH*TILE; e += 256) {
                int hh = e >> 6, tt = e & 63;
                int pg = p0 + tt; if (pg > T-1) pg = T-1;
                int qg = q0 + tt; if (qg > T-1) qg = T-1;
                float lp = lpB[(h0+hh)*T + pg];
                float mv = mB [(h0+hh)*T + pg];
                float a  = __expf(-2.f*lp);
                As [hh][tt] = a;
                AMs[hh][tt] = a * mv;
                Zs [hh][tt] = zB[(h0+hh)*T + qg];
            }
            __syncthreads();
#pragma unroll 8
            for (int hh = 0; hh < KH; ++hh) {
                const float4 av  = *(const float4*)(&As [hh][ty*4]);
                const float4 amv = *(const float4*)(&AMs[hh][ty*4]);
                const float4 zv  = *(const float4*)(&Zs [hh][tx*4]);
                const float pa[4]  = {av.x, av.y, av.z, av.w};
                const float pam[4] = {amv.x, amv.y, amv.z, amv.w};
                const float qz[4]  = {zv.x, zv.y, zv.z, zv.w};
                float qz2[4];
#pragma unroll
                for (int j = 0; j < 4; ++j) qz2[j] = qz[j] * qz[j];
#pragma unroll
                for (int ii = 0; ii < 4; ++ii)
#pragma unroll
                    for (int jj = 0; jj < 4; ++jj) {
                        acc1[ii][jj] = fmaf(pa[ii],  qz2[jj], acc1[ii][jj]);
                        acc2[ii][jj] = fmaf(pam[ii], qz[jj],  acc2[ii][jj]);
                    }
            }
            __syncthreads();
        }

        // epilogue: kl value + pad/mask, DIAG-STAGED write (verified R16)
        float* Dm = ws + DMAT_OFF + (size_t)prob * TSLAB;
#pragma unroll
        for (int ii = 0; ii < 4; ++ii) {
            int p = p0 + ty*4 + ii;
            if (p > NP-1) continue;
            int pc = p < T ? p : T-1;
            float lpv = Lp[pc];
            float c1v = C1[pc];
            bool pmv = (p < T) && (rmask[b*T + p] != 0);
#pragma unroll
            for (int jj = 0; jj < 4; ++jj) {
                int q = q0 + tx*4 + jj;
                if (q > NP-1) continue;
                int qc = q < T ? q : T-1;
                bool qmv = (q < T) && (cmask[b*T + q] != 0);
                float val = lpv - Lq[qc] - 0.5f*(float)H
                          + 0.5f*(acc1[ii][jj] - 2.f*acc2[ii][jj] + c1v);
                float outv = (pmv != qmv) ? MASK_INF_C : ((!pmv && !qmv) ? 0.f : val);
                int I8 = p >> 3, J8 = q >> 3, sdg = I8 + J8;
                int len = diag_len(sdg), i0 = diag_i0(sdg), Cs = diag_Cs(sdg);
                int k = (p & 7) * 2 + ((q & 7) >> 2);
                int off = Cs*64 + (k*len + (I8 - i0))*4 + (q & 3);
                Dm[off] = outv;
            }
        }
    } else {
        // ---------------- scalar losses path ----------------
        float s0 = 0.f, s1 = 0.f, s2 = 0.f, s3 = 0.f, s4 = 0.f, s5 = 0.f;
        int tid = (blockIdx.x - KLBLOCKS) * 256 + threadIdx.x;
        const int stride = SBLOCKS * 256;

        const float4* fr4 = (const float4*)fr;
        const float4* ff4 = (const float4*)ff;
        for (int i = tid; i < 3072000; i += stride) {
            float4 a = fr4[i], b = ff4[i];
            s2 += fabsf(a.x - b.x) + fabsf(a.y - b.y) + fabsf(a.z - b.z) + fabsf(a.w - b.w);
        }
        const float4* m4 = (const float4*)mel;
        const float4* mh4 = (const float4*)melh;
        for (int i = tid; i < 64000; i += stride) {
            float4 a = m4[i], b = mh4[i];
            s3 += fabsf(a.x - b.x) + fabsf(a.y - b.y) + fabsf(a.z - b.z) + fabsf(a.w - b.w);
        }
        const float4* g4 = (const float4*)sg;
        const float4* e4 = (const float4*)se;
        for (int i = tid; i < 4800; i += stride) {
            float4 a = g4[i], b = e4[i];
            float gx = 1.f - a.x, gy = 1.f - a.y, gz = 1.f - a.z, gw = 1.f - a.w;
            s0 += gx*gx + gy*gy + gz*gz + gw*gw;
            float hx = 1.f - b.x, hy = 1.f - b.y, hz = 1.f - b.z, hw = 1.f - b.w;
            s1 += hx*hx + hy*hy + hz*hz + hw*hw;
        }
        for (int i = tid; i < B*T; i += stride) {
            s4 += (float)p_mask[i];
            s5 += (float)z_mask[i];
        }
        for (int off = 32; off > 0; off >>= 1) {
            s0 += __shfl_down(s0, off); s1 += __shfl_down(s1, off);
            s2 += __shfl_down(s2, off); s3 += __shfl_down(s3, off);
            s4 += __shfl_down(s4, off); s5 += __shfl_down(s5, off);
        }
        int wid = threadIdx.x >> 6;
        if ((threadIdx.x & 63) == 0) {
            red[wid][0] = s0; red[wid][1] = s1; red[wid][2] = s2;
            red[wid][3] = s3; red[wid][4] = s4; red[wid][5] = s5;
        }
        __syncthreads();
        if (threadIdx.x == 0) {
            float t0 = 0.f, t1 = 0.f, t2 = 0.f, t3 = 0.f, t4 = 0.f, t5 = 0.f;
#pragma unroll
            for (int w = 0; w < 4; ++w) {
                t0 += red[w][0]; t1 += red[w][1]; t2 += red[w][2];
                t3 += red[w][3]; t4 += red[w][4]; t5 += red[w][5];
            }
            float* slot = ws + SLOT_OFF + (blockIdx.x & 7) * 16;
            atomicAdd(&slot[0], t0); atomicAdd(&slot[1], t1);
            atomicAdd(&slot[2], t2); atomicAdd(&slot[3], t3);
            atomicAdd(&slot[4], t4); atomicAdd(&slot[5], t5);
        }
    }
}

// ---------------- kernel 4: DTW tile wavefront — STANDALONE ----------------
// 16 blocks x 64 threads, launch_bounds(64,1). Tile computed along its 15
// internal anti-diagonals (R23: ~10us faster than row-serial — the 64-cell
// dependent chain became ~15 levels with up to 8-wide ILP).
__global__ __launch_bounds__(64, 1)
void dtw_diag(const float* __restrict__ Dd, float* __restrict__ acc) {
    int prob = blockIdx.x;
    int lane = threadIdx.x;
    const float* Dp = Dd + (size_t)prob * TSLAB;

    float brow[8];                      // raw bottom row of my tile
    float rightraw[8], rightW[8];       // my col-7 raw / +W
    float brold = BIGV, v00 = BIGV;
#pragma unroll
    for (int t = 0; t < 8; ++t) { brow[t] = BIGV; rightraw[t] = BIGV; rightW[t] = BIGV; }

    f32x4 bufA[16], bufB[16];

    auto load_diag = [&](int sp, f32x4* buf) {
        if (sp > 100) sp = 100;
        int len = diag_len(sp), i0 = diag_i0(sp), Cs = diag_Cs(sp);
        int pos = lane - i0;
        pos = pos < 0 ? 0 : pos;
        pos = pos > len - 1 ? len - 1 : pos;
        const float* srcb = Dp + Cs*64 + pos*4;
        int str = len * 4;
#pragma unroll
        for (int k = 0; k < 16; ++k)
            buf[k] = *(const f32x4*)(srcb + k*str);
    };

#define TILE_STEP(CUR, NXT, SVAL, DO_LOAD)                                    \
    {                                                                          \
        const int s_ = (SVAL);                                                 \
        if (DO_LOAD) {                                                         \
            load_diag(s_ + 1, NXT);                                            \
            __builtin_amdgcn_sched_barrier(0);                                 \
        }                                                                      \
        bool jz = (s_ == lane);            /* J == 0 */                        \
        float brnew = brow[7];                                                 \
        float upraw[8], upW[8];                                                \
        _Pragma("unroll")                                                      \
        for (int c = 0; c < 8; ++c) {                                          \
            upraw[c] = wave_shr1(brow[c], BIGV);                               \
            upW[c] = upraw[c] + WARP_PEN;                                      \
        }                                                                      \
        float corner = wave_shr1(brold, BIGV);                                 \
        if (jz) corner = (lane == 0) ? 0.f : BIGV;                             \
        float vr[8][8], vw[8][8];                                              \
        _Pragma("unroll")                                                      \
        for (int d = 0; d < 15; ++d) {                                         \
            _Pragma("unroll")                                                  \
            for (int r = 0; r < 8; ++r) {                                      \
                const int c = d - r;                                           \
                if (c < 0 || c > 7) continue;                                  \
                float uw = (r == 0) ? upW[c] : vw[r-1][c];                     \
                float lw = (c == 0) ? (jz ? BIGV : rightW[r]) : vw[r][c-1];    \
                float dg;                                                      \
                if (r == 0 && c == 0)      dg = corner;                        \
                else if (r == 0)           dg = upraw[c-1];                    \
                else if (c == 0)           dg = jz ? BIGV : rightraw[r-1];     \
                else                       dg = vr[r-1][c-1];                  \
                float v = fminf(fminf(uw, lw), dg) + CUR[r*2 + (c>>2)][c&3];   \
                vr[r][c] = v;                                                  \
                vw[r][c] = v + WARP_PEN;                                       \
            }                                                                  \
        }                                                                      \
        v00 = vr[0][0];                                                        \
        _Pragma("unroll")                                                      \
        for (int r = 0; r < 8; ++r) { rightraw[r] = vr[r][7]; rightW[r] = vw[r][7]; } \
        _Pragma("unroll")                                                      \
        for (int c = 0; c < 8; ++c) brow[c] = vr[7][c];                        \
        brold = brnew;                                                         \
    }

    load_diag(0, bufA);

    for (int sb = 0; sb < 100; sb += 2) {
        TILE_STEP(bufA, bufB, sb,     1)
        TILE_STEP(bufB, bufA, sb + 1, 1)
    }
    TILE_STEP(bufA, bufB, 100, 0)   // final tile-diagonal
#undef TILE_STEP

    // R[400][400] = tile(50,50) cell (0,0), computed at s=100 by lane 50
    if (lane == 50) atomicAdd(&acc[6 + (prob >> 3)], v00);
}

// ---------------- kernel 5: assemble outputs ----------------
__global__ void finalize(const float* __restrict__ acc,
                         const float* __restrict__ dur,
                         const float* __restrict__ pit,
                         float* __restrict__ out) {
    if (threadIdx.x != 0 || blockIdx.x != 0) return;
    float t[6] = {0.f, 0.f, 0.f, 0.f, 0.f, 0.f};
    for (int s = 0; s < 8; ++s)
        for (int c = 0; c < 6; ++c)
            t[c] += acc[SLOT_OFF + s*16 + c];
    float gen  = t[0] / 3200.f;
    float e2e  = t[1] / 3200.f;
    float fm   = 4.f * t[2] / 409600.f;
    float melv = 45.f * t[3] / 256000.f;
    float d    = dur[0];
    float p    = pit[0];
    float kl   = acc[6] / t[4];
    float klf  = acc[7] / t[5];
    out[0] = gen; out[1] = e2e; out[2] = fm; out[3] = melv;
    out[4] = d;   out[5] = p;   out[6] = kl; out[7] = klf;
    out[8] = gen + e2e + fm + melv + d + p + kl + klf;
}

// ---------------- launch ----------------
extern "C" void kernel_launch(void* const* d_in, const int* in_sizes, int n_in,
                              void* d_out, int out_size, void* d_ws, size_t ws_size,
                              hipStream_t stream) {
    const float* mel    = (const float*)d_in[0];
    const float* melh   = (const float*)d_in[1];
    const float* sg     = (const float*)d_in[2];
    const float* se     = (const float*)d_in[3];
    const float* fr     = (const float*)d_in[4];
    const float* ff     = (const float*)d_in[5];
    const float* dur    = (const float*)d_in[6];
    const float* pit    = (const float*)d_in[7];
    const float* z_p    = (const float*)d_in[8];
    const float* m_p    = (const float*)d_in[9];
    const float* logs_p = (const float*)d_in[10];
    const float* z_q    = (const float*)d_in[11];
    const float* m_q    = (const float*)d_in[12];
    const float* logs_q = (const float*)d_in[13];
    const int*   p_mask = (const int*)d_in[14];
    const int*   z_mask = (const int*)d_in[15];
    float* ws  = (float*)d_ws;
    float* out = (float*)d_out;

    hipMemsetAsync(ws, 0, 160 * sizeof(float), stream);
    colsum<<<B*7, 256, 0, stream>>>(logs_p, m_p, logs_q, m_q, ws);
    fused_kl_scalar<<<KLBLOCKS + SBLOCKS, 256, 0, stream>>>(
        z_p, m_p, logs_p, z_q, m_q, logs_q, p_mask, z_mask, ws,
        mel, melh, sg, se, fr, ff);
    dtw_diag<<<NPROB, 64, 0, stream>>>(ws + DMAT_OFF, ws);
    finalize<<<1, 64, 0, stream>>>(ws, dur, pit, out);
}

// Round 25
// 140.662 us; speedup vs baseline: 1.4777x; 1.1061x over previous
//
#include <hip/hip_runtime.h>
#include <math.h>

// ---------------- constants ----------------
#define BIGV      1e9f
#define WARP_PEN  134.4f
#define MASK_INF_C 100000.0f

#define B   8
#define H   192
#define T   400
#define NP  401                  // padded matrix dim (0..400)
#define NPROB 16                 // 2 dirs x 8 batches
#define TSLAB 166464             // diag-staged D floats per problem (2601 tiles x 64)
#define SBLOCKS 768              // scalar-loss blocks
#define KLBLOCKS (49 * NPROB)    // 784 kl_gemm blocks (64x64 tiles)

typedef float f32x4 __attribute__((ext_vector_type(4)));

// ---------------- workspace layout (float offsets) ----------------
#define SLOT_OFF 16
#define LSP_OFF 160
#define LSQ_OFF (160 + B*T)
#define C1P_OFF (160 + 2*B*T)
#define C1Q_OFF (160 + 3*B*T)
#define DMAT_OFF (160 + 4*B*T)   // 12960 floats, 16B aligned

// Diagonal-staged tile layout (verified R16-R24).
__device__ __forceinline__ int diag_len(int s) { return (s <= 50) ? s + 1 : 101 - s; }
__device__ __forceinline__ int diag_i0 (int s) { return (s <= 50) ? 0 : s - 50; }
__device__ __forceinline__ int diag_Cs (int s) {
    return (s <= 51) ? s * (s + 1) / 2 : 2601 - (101 - s) * (102 - s) / 2;
}

// DPP wave_shr:1 — lane i gets src from lane i-1; lane 0 gets `fill`.
__device__ __forceinline__ float wave_shr1(float src, float fill) {
    int r = __builtin_amdgcn_update_dpp(__float_as_int(fill), __float_as_int(src),
                                        0x138 /*wave_shr:1*/, 0xf, 0xf, false);
    return __int_as_float(r);
}

// ---------------- kernel 2: per-(b,t) column sums (4-way h-split) ----------
__global__ __launch_bounds__(256)
void colsum(const float* __restrict__ logs_p, const float* __restrict__ m_p,
            const float* __restrict__ logs_q, const float* __restrict__ m_q,
            float* __restrict__ ws) {
    int b = blockIdx.x / 7;
    int lane = threadIdx.x & 63;
    int hq = threadIdx.x >> 6;                 // 0..3, 48 h each
    int t = (blockIdx.x % 7) * 64 + lane;
    __shared__ float part[4][4][64];
    float lp_s = 0.f, lq_s = 0.f, c1p = 0.f, c1q = 0.f;
    if (t < T) {
        int base = b*H*T + hq*48*T + t;
        const float* LP = logs_p + base;
        const float* MP = m_p   + base;
        const float* LQ = logs_q + base;
        const float* MQ = m_q   + base;
#pragma unroll 4
        for (int h = 0; h < 48; ++h) {
            float lp = LP[h*T], mp = MP[h*T];
            float lq = LQ[h*T], mq = MQ[h*T];
            lp_s += lp;
            lq_s += lq;
            c1p += __expf(-2.f*lp) * mp * mp;
            c1q += __expf(-2.f*lq) * mq * mq;
        }
    }
    part[hq][0][lane] = lp_s;
    part[hq][1][lane] = lq_s;
    part[hq][2][lane] = c1p;
    part[hq][3][lane] = c1q;
    __syncthreads();
    if (hq == 0 && t < T) {
        float a0 = part[0][0][lane] + part[1][0][lane] + part[2][0][lane] + part[3][0][lane];
        float a1 = part[0][1][lane] + part[1][1][lane] + part[2][1][lane] + part[3][1][lane];
        float a2 = part[0][2][lane] + part[1][2][lane] + part[2][2][lane] + part[3][2][lane];
        float a3 = part[0][3][lane] + part[1][3][lane] + part[2][3][lane] + part[3][3][lane];
        ws[LSP_OFF + b*T + t] = a0;
        ws[LSQ_OFF + b*T + t] = a1;
        ws[C1P_OFF + b*T + t] = a2;
        ws[C1Q_OFF + b*T + t] = a3;
    }
}

// ---------------- fused kernel: KL GEMM (blocks 0..783) + scalar losses ----
// EXACT R20 config (proven 70us): 64x64 tile, KH=32, Z2s precomputed in LDS
// during staging (R24 showed removing it lengthens the ds_read->FMA critical
// path: 85us). Latency-bound at ~33% VALUBusy.
#define TILE 64
#define KH 32
__global__ __launch_bounds__(256)
void fused_kl_scalar(const float* __restrict__ z_p, const float* __restrict__ m_p,
                     const float* __restrict__ logs_p,
                     const float* __restrict__ z_q, const float* __restrict__ m_q,
                     const float* __restrict__ logs_q,
                     const int* __restrict__ p_mask, const int* __restrict__ z_mask,
                     float* __restrict__ ws,
                     const float* __restrict__ mel, const float* __restrict__ melh,
                     const float* __restrict__ sg,  const float* __restrict__ se,
                     const float* __restrict__ fr,  const float* __restrict__ ff) {
    __shared__ __align__(16) float As [KH][TILE+4];
    __shared__ __align__(16) float AMs[KH][TILE+4];
    __shared__ __align__(16) float Zs [KH][TILE+4];
    __shared__ __align__(16) float Z2s[KH][TILE+4];
    __shared__ float red[4][8];

    if (blockIdx.x < KLBLOCKS) {
        // ---------------- kl_gemm path ----------------
        int prob = blockIdx.x / 49;
        int bx   = blockIdx.x % 49;
        int dir = prob >> 3, b = prob & 7;
        int tp = bx / 7, tq = bx % 7;
        int p0 = tp * TILE, q0 = tq * TILE;

        const float* lp_arr = dir ? logs_q : logs_p;
        const float* m_arr  = dir ? m_q    : m_p;
        const float* z_arr  = dir ? z_q    : z_p;
        const float* Lp = ws + (dir ? LSQ_OFF : LSP_OFF) + b*T;
        const float* Lq = ws + (dir ? LSP_OFF : LSQ_OFF) + b*T;
        const float* C1 = ws + (dir ? C1Q_OFF : C1P_OFF) + b*T;
        const int* rmask = dir ? z_mask : p_mask;
        const int* cmask = dir ? p_mask : z_mask;

        int tid = threadIdx.x;
        int tx = tid & 15, ty = tid >> 4;

        float acc1[4][4] = {{0.f}}, acc2[4][4] = {{0.f}};

        const float* lpB = lp_arr + b*H*T;
        const float* mB  = m_arr  + b*H*T;
        const float* zB  = z_arr  + b*H*T;

        for (int h0 = 0; h0 < H; h0 += KH) {
            for (int e = tid; e < KH*TILE; e += 256) {
                int hh = e >> 6, tt = e & 63;
                int pg = p0 + tt; if (pg > T-1) pg = T-1;
                int qg = q0 + tt; if (qg > T-1) qg = T-1;
                float lp = lpB[(h0+hh)*T + pg];
                float mv = mB [(h0+hh)*T + pg];
                float a  = __expf(-2.f*lp);
                As [hh][tt] = a;
                AMs[hh][tt] = a * mv;
                float zv = zB[(h0+hh)*T + qg];
                Zs [hh][tt] = zv;
                Z2s[hh][tt] = zv * zv;
            }
            __syncthreads();
#pragma unroll 8
            for (int hh = 0; hh < KH; ++hh) {
                const float4 av  = *(const float4*)(&As [hh][ty*4]);
                const float4 amv = *(const float4*)(&AMs[hh][ty*4]);
                const float4 zv  = *(const float4*)(&Zs [hh][tx*4]);
                const float4 z2v = *(const float4*)(&Z2s[hh][tx*4]);
                const float pa[4]  = {av.x, av.y, av.z, av.w};
                const float pam[4] = {amv.x, amv.y, amv.z, amv.w};
                const float qz[4]  = {zv.x, zv.y, zv.z, zv.w};
                const float qz2[4] = {z2v.x, z2v.y, z2v.z, z2v.w};
#pragma unroll
                for (int ii = 0; ii < 4; ++ii)
#pragma unroll
                    for (int jj = 0; jj < 4; ++jj) {
                        acc1[ii][jj] = fmaf(pa[ii],  qz2[jj], acc1[ii][jj]);
                        acc2[ii][jj] = fmaf(pam[ii], qz[jj],  acc2[ii][jj]);
                    }
            }
            __syncthreads();
        }

        // epilogue: kl value + pad/mask, DIAG-STAGED write (verified R16)
        float* Dm = ws + DMAT_OFF + (size_t)prob * TSLAB;
#pragma unroll
        for (int ii = 0; ii < 4; ++ii) {
            int p = p0 + ty*4 + ii;
            if (p > NP-1) continue;
            int pc = p < T ? p : T-1;
            float lpv = Lp[pc];
            float c1v = C1[pc];
            bool pmv = (p < T) && (rmask[b*T + p] != 0);
#pragma unroll
            for (int jj = 0; jj < 4; ++jj) {
                int q = q0 + tx*4 + jj;
                if (q > NP-1) continue;
                int qc = q < T ? q : T-1;
                bool qmv = (q < T) && (cmask[b*T + q] != 0);
                float val = lpv - Lq[qc] - 0.5f*(float)H
                          + 0.5f*(acc1[ii][jj] - 2.f*acc2[ii][jj] + c1v);
                float outv = (pmv != qmv) ? MASK_INF_C : ((!pmv && !qmv) ? 0.f : val);
                int I8 = p >> 3, J8 = q >> 3, sdg = I8 + J8;
                int len = diag_len(sdg), i0 = diag_i0(sdg), Cs = diag_Cs(sdg);
                int k = (p & 7) * 2 + ((q & 7) >> 2);
                int off = Cs*64 + (k*len + (I8 - i0))*4 + (q & 3);
                Dm[off] = outv;
            }
        }
    } else {
        // ---------------- scalar losses path ----------------
        float s0 = 0.f, s1 = 0.f, s2 = 0.f, s3 = 0.f, s4 = 0.f, s5 = 0.f;
        int tid = (blockIdx.x - KLBLOCKS) * 256 + threadIdx.x;
        const int stride = SBLOCKS * 256;

        const float4* fr4 = (const float4*)fr;
        const float4* ff4 = (const float4*)ff;
        for (int i = tid; i < 3072000; i += stride) {
            float4 a = fr4[i], b = ff4[i];
            s2 += fabsf(a.x - b.x) + fabsf(a.y - b.y) + fabsf(a.z - b.z) + fabsf(a.w - b.w);
        }
        const float4* m4 = (const float4*)mel;
        const float4* mh4 = (const float4*)melh;
        for (int i = tid; i < 64000; i += stride) {
            float4 a = m4[i], b = mh4[i];
            s3 += fabsf(a.x - b.x) + fabsf(a.y - b.y) + fabsf(a.z - b.z) + fabsf(a.w - b.w);
        }
        const float4* g4 = (const float4*)sg;
        const float4* e4 = (const float4*)se;
        for (int i = tid; i < 4800; i += stride) {
            float4 a = g4[i], b = e4[i];
            float gx = 1.f - a.x, gy = 1.f - a.y, gz = 1.f - a.z, gw = 1.f - a.w;
            s0 += gx*gx + gy*gy + gz*gz + gw*gw;
            float hx = 1.f - b.x, hy = 1.f - b.y, hz = 1.f - b.z, hw = 1.f - b.w;
            s1 += hx*hx + hy*hy + hz*hz + hw*hw;
        }
        for (int i = tid; i < B*T; i += stride) {
            s4 += (float)p_mask[i];
            s5 += (float)z_mask[i];
        }
        for (int off = 32; off > 0; off >>= 1) {
            s0 += __shfl_down(s0, off); s1 += __shfl_down(s1, off);
            s2 += __shfl_down(s2, off); s3 += __shfl_down(s3, off);
            s4 += __shfl_down(s4, off); s5 += __shfl_down(s5, off);
        }
        int wid = threadIdx.x >> 6;
        if ((threadIdx.x & 63) == 0) {
            red[wid][0] = s0; red[wid][1] = s1; red[wid][2] = s2;
            red[wid][3] = s3; red[wid][4] = s4; red[wid][5] = s5;
        }
        __syncthreads();
        if (threadIdx.x == 0) {
            float t0 = 0.f, t1 = 0.f, t2 = 0.f, t3 = 0.f, t4 = 0.f, t5 = 0.f;
#pragma unroll
            for (int w = 0; w < 4; ++w) {
                t0 += red[w][0]; t1 += red[w][1]; t2 += red[w][2];
                t3 += red[w][3]; t4 += red[w][4]; t5 += red[w][5];
            }
            float* slot = ws + SLOT_OFF + (blockIdx.x & 7) * 16;
            atomicAdd(&slot[0], t0); atomicAdd(&slot[1], t1);
            atomicAdd(&slot[2], t2); atomicAdd(&slot[3], t3);
            atomicAdd(&slot[4], t4); atomicAdd(&slot[5], t5);
        }
    }
}

// ---------------- kernel 4: DTW tile wavefront — STANDALONE ----------------
// 16 blocks x 64 threads, launch_bounds(64,1). Tile computed along its 15
// internal anti-diagonals (R23: ~10us faster than row-serial — the 64-cell
// dependent chain became ~15 levels with up to 8-wide ILP).
__global__ __launch_bounds__(64, 1)
void dtw_diag(const float* __restrict__ Dd, float* __restrict__ acc) {
    int prob = blockIdx.x;
    int lane = threadIdx.x;
    const float* Dp = Dd + (size_t)prob * TSLAB;

    float brow[8];                      // raw bottom row of my tile
    float rightraw[8], rightW[8];       // my col-7 raw / +W
    float brold = BIGV, v00 = BIGV;
#pragma unroll
    for (int t = 0; t < 8; ++t) { brow[t] = BIGV; rightraw[t] = BIGV; rightW[t] = BIGV; }

    f32x4 bufA[16], bufB[16];

    auto load_diag = [&](int sp, f32x4* buf) {
        if (sp > 100) sp = 100;
        int len = diag_len(sp), i0 = diag_i0(sp), Cs = diag_Cs(sp);
        int pos = lane - i0;
        pos = pos < 0 ? 0 : pos;
        pos = pos > len - 1 ? len - 1 : pos;
        const float* srcb = Dp + Cs*64 + pos*4;
        int str = len * 4;
#pragma unroll
        for (int k = 0; k < 16; ++k)
            buf[k] = *(const f32x4*)(srcb + k*str);
    };

#define TILE_STEP(CUR, NXT, SVAL, DO_LOAD)                                    \
    {                                                                          \
        const int s_ = (SVAL);                                                 \
        if (DO_LOAD) {                                                         \
            load_diag(s_ + 1, NXT);                                            \
            __builtin_amdgcn_sched_barrier(0);                                 \
        }                                                                      \
        bool jz = (s_ == lane);            /* J == 0 */                        \
        float brnew = brow[7];                                                 \
        float upraw[8], upW[8];                                                \
        _Pragma("unroll")                                                      \
        for (int c = 0; c < 8; ++c) {                                          \
            upraw[c] = wave_shr1(brow[c], BIGV);                               \
            upW[c] = upraw[c] + WARP_PEN;                                      \
        }                                                                      \
        float corner = wave_shr1(brold, BIGV);                                 \
        if (jz) corner = (lane == 0) ? 0.f : BIGV;                             \
        float vr[8][8], vw[8][8];                                              \
        _Pragma("unroll")                                                      \
        for (int d = 0; d < 15; ++d) {                                         \
            _Pragma("unroll")                                                  \
            for (int r = 0; r < 8; ++r) {                                      \
                const int c = d - r;                                           \
                if (c < 0 || c > 7) continue;                                  \
                float uw = (r == 0) ? upW[c] : vw[r-1][c];                     \
                float lw = (c == 0) ? (jz ? BIGV : rightW[r]) : vw[r][c-1];    \
                float dg;                                                      \
                if (r == 0 && c == 0)      dg = corner;                        \
                else if (r == 0)           dg = upraw[c-1];                    \
                else if (c == 0)           dg = jz ? BIGV : rightraw[r-1];     \
                else                       dg = vr[r-1][c-1];                  \
                float v = fminf(fminf(uw, lw), dg) + CUR[r*2 + (c>>2)][c&3];   \
                vr[r][c] = v;                                                  \
                vw[r][c] = v + WARP_PEN;                                       \
            }                                                                  \
        }                                                                      \
        v00 = vr[0][0];                                                        \
        _Pragma("unroll")                                                      \
        for (int r = 0; r < 8; ++r) { rightraw[r] = vr[r][7]; rightW[r] = vw[r][7]; } \
        _Pragma("unroll")                                                      \
        for (int c = 0; c < 8; ++c) brow[c] = vr[7][c];                        \
        brold = brnew;                                                         \
    }

    load_diag(0, bufA);

    for (int sb = 0; sb < 100; sb += 2) {
        TILE_STEP(bufA, bufB, sb,     1)
        TILE_STEP(bufB, bufA, sb + 1, 1)
    }
    TILE_STEP(bufA, bufB, 100, 0)   // final tile-diagonal
#undef TILE_STEP

    // R[400][400] = tile(50,50) cell (0,0), computed at s=100 by lane 50
    if (lane == 50) atomicAdd(&acc[6 + (prob >> 3)], v00);
}

// ---------------- kernel 5: assemble outputs ----------------
__global__ void finalize(const float* __restrict__ acc,
                         const float* __restrict__ dur,
                         const float* __restrict__ pit,
                         float* __restrict__ out) {
    if (threadIdx.x != 0 || blockIdx.x != 0) return;
    float t[6] = {0.f, 0.f, 0.f, 0.f, 0.f, 0.f};
    for (int s = 0; s < 8; ++s)
        for (int c = 0; c < 6; ++c)
            t[c] += acc[SLOT_OFF + s*16 + c];
    float gen  = t[0] / 3200.f;
    float e2e  = t[1] / 3200.f;
    float fm   = 4.f * t[2] / 409600.f;
    float melv = 45.f * t[3] / 256000.f;
    float d    = dur[0];
    float p    = pit[0];
    float kl   = acc[6] / t[4];
    float klf  = acc[7] / t[5];
    out[0] = gen; out[1] = e2e; out[2] = fm; out[3] = melv;
    out[4] = d;   out[5] = p;   out[6] = kl; out[7] = klf;
    out[8] = gen + e2e + fm + melv + d + p + kl + klf;
}

// ---------------- launch ----------------
extern "C" void kernel_launch(void* const* d_in, const int* in_sizes, int n_in,
                              void* d_out, int out_size, void* d_ws, size_t ws_size,
                              hipStream_t stream) {
    const float* mel    = (const float*)d_in[0];
    const float* melh   = (const float*)d_in[1];
    const float* sg     = (const float*)d_in[2];
    const float* se     = (const float*)d_in[3];
    const float* fr     = (const float*)d_in[4];
    const float* ff     = (const float*)d_in[5];
    const float* dur    = (const float*)d_in[6];
    const float* pit    = (const float*)d_in[7];
    const float* z_p    = (const float*)d_in[8];
    const float* m_p    = (const float*)d_in[9];
    const float* logs_p = (const float*)d_in[10];
    const float* z_q    = (const float*)d_in[11];
    const float* m_q    = (const float*)d_in[12];
    const float* logs_q = (const float*)d_in[13];
    const int*   p_mask = (const int*)d_in[14];
    const int*   z_mask = (const int*)d_in[15];
    float* ws  = (float*)d_ws;
    float* out = (float*)d_out;

    hipMemsetAsync(ws, 0, 160 * sizeof(float), stream);
    colsum<<<B*7, 256, 0, stream>>>(logs_p, m_p, logs_q, m_q, ws);
    fused_kl_scalar<<<KLBLOCKS + SBLOCKS, 256, 0, stream>>>(
        z_p, m_p, logs_p, z_q, m_q, logs_q, p_mask, z_mask, ws,
        mel, melh, sg, se, fr, ff);
    dtw_diag<<<NPROB, 64, 0, stream>>>(ws + DMAT_OFF, ws);
    finalize<<<1, 64, 0, stream>>>(ws, dur, pit, out);
}

// Round 26
// 136.105 us; speedup vs baseline: 1.5272x; 1.0335x over previous
//
#include <hip/hip_runtime.h>
#include <math.h>

// ---------------- constants ----------------
#define BIGV      1e9f
#define WARP_PEN  134.4f
#define MASK_INF_C 100000.0f

#define B   8
#define H   192
#define T   400
#define NP  401                  // padded matrix dim (0..400)
#define NPROB 16                 // 2 dirs x 8 batches
#define TSLAB 166464             // diag-staged D floats per problem (2601 tiles x 64)
#define SBLOCKS 768              // scalar-loss blocks
#define KLBLOCKS (49 * NPROB)    // 784 kl_gemm blocks (64x64 tiles)

typedef float f32x4 __attribute__((ext_vector_type(4)));

// ---------------- workspace layout (float offsets) ----------------
#define SLOT_OFF 16
#define LSP_OFF 160
#define LSQ_OFF (160 + B*T)
#define C1P_OFF (160 + 2*B*T)
#define C1Q_OFF (160 + 3*B*T)
#define DMAT_OFF (160 + 4*B*T)   // 12960 floats, 16B aligned

// Diagonal-staged tile layout (verified R16-R25).
__device__ __forceinline__ int diag_len(int s) { return (s <= 50) ? s + 1 : 101 - s; }
__device__ __forceinline__ int diag_i0 (int s) { return (s <= 50) ? 0 : s - 50; }
__device__ __forceinline__ int diag_Cs (int s) {
    return (s <= 51) ? s * (s + 1) / 2 : 2601 - (101 - s) * (102 - s) / 2;
}

// DPP wave_shr:1 — lane i gets src from lane i-1; lane 0 gets `fill`.
__device__ __forceinline__ float wave_shr1(float src, float fill) {
    int r = __builtin_amdgcn_update_dpp(__float_as_int(fill), __float_as_int(src),
                                        0x138 /*wave_shr:1*/, 0xf, 0xf, false);
    return __int_as_float(r);
}

// ---------------- kernel 2: per-(b,t) column sums (4-way h-split) ----------
__global__ __launch_bounds__(256)
void colsum(const float* __restrict__ logs_p, const float* __restrict__ m_p,
            const float* __restrict__ logs_q, const float* __restrict__ m_q,
            float* __restrict__ ws) {
    int b = blockIdx.x / 7;
    int lane = threadIdx.x & 63;
    int hq = threadIdx.x >> 6;                 // 0..3, 48 h each
    int t = (blockIdx.x % 7) * 64 + lane;
    __shared__ float part[4][4][64];
    float lp_s = 0.f, lq_s = 0.f, c1p = 0.f, c1q = 0.f;
    if (t < T) {
        int base = b*H*T + hq*48*T + t;
        const float* LP = logs_p + base;
        const float* MP = m_p   + base;
        const float* LQ = logs_q + base;
        const float* MQ = m_q   + base;
#pragma unroll 4
        for (int h = 0; h < 48; ++h) {
            float lp = LP[h*T], mp = MP[h*T];
            float lq = LQ[h*T], mq = MQ[h*T];
            lp_s += lp;
            lq_s += lq;
            c1p += __expf(-2.f*lp) * mp * mp;
            c1q += __expf(-2.f*lq) * mq * mq;
        }
    }
    part[hq][0][lane] = lp_s;
    part[hq][1][lane] = lq_s;
    part[hq][2][lane] = c1p;
    part[hq][3][lane] = c1q;
    __syncthreads();
    if (hq == 0 && t < T) {
        float a0 = part[0][0][lane] + part[1][0][lane] + part[2][0][lane] + part[3][0][lane];
        float a1 = part[0][1][lane] + part[1][1][lane] + part[2][1][lane] + part[3][1][lane];
        float a2 = part[0][2][lane] + part[1][2][lane] + part[2][2][lane] + part[3][2][lane];
        float a3 = part[0][3][lane] + part[1][3][lane] + part[2][3][lane] + part[3][3][lane];
        ws[LSP_OFF + b*T + t] = a0;
        ws[LSQ_OFF + b*T + t] = a1;
        ws[C1P_OFF + b*T + t] = a2;
        ws[C1Q_OFF + b*T + t] = a3;
    }
}

// ---------------- fused kernel: KL GEMM (blocks 0..783) + scalar losses ----
// R20 config + T14 async-STAGE split: chunk c+1's 24 global loads issue into
// REGISTERS before computing chunk c (2240cy FMA covers ~900cy latency);
// LDS write happens after the compute barrier (vmcnt wait fully hidden).
// Removes the per-chunk exposed staging latency that held VALUBusy at 33%.
#define TILE 64
#define KH 32
#define NCHUNK (H / KH)
__global__ __launch_bounds__(256)
void fused_kl_scalar(const float* __restrict__ z_p, const float* __restrict__ m_p,
                     const float* __restrict__ logs_p,
                     const float* __restrict__ z_q, const float* __restrict__ m_q,
                     const float* __restrict__ logs_q,
                     const int* __restrict__ p_mask, const int* __restrict__ z_mask,
                     float* __restrict__ ws,
                     const float* __restrict__ mel, const float* __restrict__ melh,
                     const float* __restrict__ sg,  const float* __restrict__ se,
                     const float* __restrict__ fr,  const float* __restrict__ ff) {
    __shared__ __align__(16) float As [KH][TILE+4];
    __shared__ __align__(16) float AMs[KH][TILE+4];
    __shared__ __align__(16) float Zs [KH][TILE+4];
    __shared__ __align__(16) float Z2s[KH][TILE+4];
    __shared__ float red[4][8];

    if (blockIdx.x < KLBLOCKS) {
        // ---------------- kl_gemm path ----------------
        int prob = blockIdx.x / 49;
        int bx   = blockIdx.x % 49;
        int dir = prob >> 3, b = prob & 7;
        int tp = bx / 7, tq = bx % 7;
        int p0 = tp * TILE, q0 = tq * TILE;

        const float* lp_arr = dir ? logs_q : logs_p;
        const float* m_arr  = dir ? m_q    : m_p;
        const float* z_arr  = dir ? z_q    : z_p;
        const float* Lp = ws + (dir ? LSQ_OFF : LSP_OFF) + b*T;
        const float* Lq = ws + (dir ? LSP_OFF : LSQ_OFF) + b*T;
        const float* C1 = ws + (dir ? C1Q_OFF : C1P_OFF) + b*T;
        const int* rmask = dir ? z_mask : p_mask;
        const int* cmask = dir ? p_mask : z_mask;

        int tid = threadIdx.x;
        int tx = tid & 15, ty = tid >> 4;
        int ty4 = tid >> 6, tts = tid & 63;       // staging row-group / column

        float acc1[4][4] = {{0.f}}, acc2[4][4] = {{0.f}};

        const float* lpB = lp_arr + b*H*T;
        const float* mB  = m_arr  + b*H*T;
        const float* zB  = z_arr  + b*H*T;

        int pg = p0 + tts; if (pg > T-1) pg = T-1;
        int qg = q0 + tts; if (qg > T-1) qg = T-1;

        float lpv[8], mvv[8], zvv[8];
        // prologue: load chunk 0 into registers
#pragma unroll
        for (int k = 0; k < 8; ++k) {
            int hh = ty4 + 4*k;
            lpv[k] = lpB[hh*T + pg];
            mvv[k] = mB [hh*T + pg];
            zvv[k] = zB [hh*T + qg];
        }
        // write chunk 0 to LDS
#pragma unroll
        for (int k = 0; k < 8; ++k) {
            int hh = ty4 + 4*k;
            float a = __expf(-2.f*lpv[k]);
            As [hh][tts] = a;
            AMs[hh][tts] = a * mvv[k];
            Zs [hh][tts] = zvv[k];
            Z2s[hh][tts] = zvv[k]*zvv[k];
        }
        __syncthreads();

        for (int c = 0; c < NCHUNK; ++c) {
            // issue next chunk's loads BEFORE compute (T14: latency hides
            // under the 32-hh FMA phase)
            if (c < NCHUNK-1) {
                int h0n = (c+1)*KH;
#pragma unroll
                for (int k = 0; k < 8; ++k) {
                    int hh = h0n + ty4 + 4*k;
                    lpv[k] = lpB[hh*T + pg];
                    mvv[k] = mB [hh*T + pg];
                    zvv[k] = zB [hh*T + qg];
                }
                __builtin_amdgcn_sched_barrier(0);  // pin load issue here
            }
#pragma unroll 8
            for (int hh = 0; hh < KH; ++hh) {
                const float4 av  = *(const float4*)(&As [hh][ty*4]);
                const float4 amv = *(const float4*)(&AMs[hh][ty*4]);
                const float4 zv  = *(const float4*)(&Zs [hh][tx*4]);
                const float4 z2v = *(const float4*)(&Z2s[hh][tx*4]);
                const float pa[4]  = {av.x, av.y, av.z, av.w};
                const float pam[4] = {amv.x, amv.y, amv.z, amv.w};
                const float qz[4]  = {zv.x, zv.y, zv.z, zv.w};
                const float qz2[4] = {z2v.x, z2v.y, z2v.z, z2v.w};
#pragma unroll
                for (int ii = 0; ii < 4; ++ii)
#pragma unroll
                    for (int jj = 0; jj < 4; ++jj) {
                        acc1[ii][jj] = fmaf(pa[ii],  qz2[jj], acc1[ii][jj]);
                        acc2[ii][jj] = fmaf(pam[ii], qz[jj],  acc2[ii][jj]);
                    }
            }
            __syncthreads();   // all reads of LDS[cur] complete
            if (c < NCHUNK-1) {
#pragma unroll
                for (int k = 0; k < 8; ++k) {
                    int hh = ty4 + 4*k;
                    float a = __expf(-2.f*lpv[k]);
                    As [hh][tts] = a;
                    AMs[hh][tts] = a * mvv[k];
                    Zs [hh][tts] = zvv[k];
                    Z2s[hh][tts] = zvv[k]*zvv[k];
                }
                __syncthreads();
            }
        }

        // epilogue: kl value + pad/mask, DIAG-STAGED write (verified R16)
        float* Dm = ws + DMAT_OFF + (size_t)prob * TSLAB;
#pragma unroll
        for (int ii = 0; ii < 4; ++ii) {
            int p = p0 + ty*4 + ii;
            if (p > NP-1) continue;
            int pc = p < T ? p : T-1;
            float lpvv = Lp[pc];
            float c1v = C1[pc];
            bool pmv = (p < T) && (rmask[b*T + p] != 0);
#pragma unroll
            for (int jj = 0; jj < 4; ++jj) {
                int q = q0 + tx*4 + jj;
                if (q > NP-1) continue;
                int qc = q < T ? q : T-1;
                bool qmv = (q < T) && (cmask[b*T + q] != 0);
                float val = lpvv - Lq[qc] - 0.5f*(float)H
                          + 0.5f*(acc1[ii][jj] - 2.f*acc2[ii][jj] + c1v);
                float outv = (pmv != qmv) ? MASK_INF_C : ((!pmv && !qmv) ? 0.f : val);
                int I8 = p >> 3, J8 = q >> 3, sdg = I8 + J8;
                int len = diag_len(sdg), i0 = diag_i0(sdg), Cs = diag_Cs(sdg);
                int k = (p & 7) * 2 + ((q & 7) >> 2);
                int off = Cs*64 + (k*len + (I8 - i0))*4 + (q & 3);
                Dm[off] = outv;
            }
        }
    } else {
        // ---------------- scalar losses path ----------------
        float s0 = 0.f, s1 = 0.f, s2 = 0.f, s3 = 0.f, s4 = 0.f, s5 = 0.f;
        int tid = (blockIdx.x - KLBLOCKS) * 256 + threadIdx.x;
        const int stride = SBLOCKS * 256;

        const float4* fr4 = (const float4*)fr;
        const float4* ff4 = (const float4*)ff;
        for (int i = tid; i < 3072000; i += stride) {
            float4 a = fr4[i], b = ff4[i];
            s2 += fabsf(a.x - b.x) + fabsf(a.y - b.y) + fabsf(a.z - b.z) + fabsf(a.w - b.w);
        }
        const float4* m4 = (const float4*)mel;
        const float4* mh4 = (const float4*)melh;
        for (int i = tid; i < 64000; i += stride) {
            float4 a = m4[i], b = mh4[i];
            s3 += fabsf(a.x - b.x) + fabsf(a.y - b.y) + fabsf(a.z - b.z) + fabsf(a.w - b.w);
        }
        const float4* g4 = (const float4*)sg;
        const float4* e4 = (const float4*)se;
        for (int i = tid; i < 4800; i += stride) {
            float4 a = g4[i], b = e4[i];
            float gx = 1.f - a.x, gy = 1.f - a.y, gz = 1.f - a.z, gw = 1.f - a.w;
            s0 += gx*gx + gy*gy + gz*gz + gw*gw;
            float hx = 1.f - b.x, hy = 1.f - b.y, hz = 1.f - b.z, hw = 1.f - b.w;
            s1 += hx*hx + hy*hy + hz*hz + hw*hw;
        }
        for (int i = tid; i < B*T; i += stride) {
            s4 += (float)p_mask[i];
            s5 += (float)z_mask[i];
        }
        for (int off = 32; off > 0; off >>= 1) {
            s0 += __shfl_down(s0, off); s1 += __shfl_down(s1, off);
            s2 += __shfl_down(s2, off); s3 += __shfl_down(s3, off);
            s4 += __shfl_down(s4, off); s5 += __shfl_down(s5, off);
        }
        int wid = threadIdx.x >> 6;
        if ((threadIdx.x & 63) == 0) {
            red[wid][0] = s0; red[wid][1] = s1; red[wid][2] = s2;
            red[wid][3] = s3; red[wid][4] = s4; red[wid][5] = s5;
        }
        __syncthreads();
        if (threadIdx.x == 0) {
            float t0 = 0.f, t1 = 0.f, t2 = 0.f, t3 = 0.f, t4 = 0.f, t5 = 0.f;
#pragma unroll
            for (int w = 0; w < 4; ++w) {
                t0 += red[w][0]; t1 += red[w][1]; t2 += red[w][2];
                t3 += red[w][3]; t4 += red[w][4]; t5 += red[w][5];
            }
            float* slot = ws + SLOT_OFF + (blockIdx.x & 7) * 16;
            atomicAdd(&slot[0], t0); atomicAdd(&slot[1], t1);
            atomicAdd(&slot[2], t2); atomicAdd(&slot[3], t3);
            atomicAdd(&slot[4], t4); atomicAdd(&slot[5], t5);
        }
    }
}

// ---------------- kernel 4: DTW tile wavefront — STANDALONE ----------------
// 16 blocks x 64 threads, launch_bounds(64,1). Tile computed along its 15
// internal anti-diagonals (8-wide ILP vs the serial 64-cell chain).
__global__ __launch_bounds__(64, 1)
void dtw_diag(const float* __restrict__ Dd, float* __restrict__ acc) {
    int prob = blockIdx.x;
    int lane = threadIdx.x;
    const float* Dp = Dd + (size_t)prob * TSLAB;

    float brow[8];                      // raw bottom row of my tile
    float rightraw[8], rightW[8];       // my col-7 raw / +W
    float brold = BIGV, v00 = BIGV;
#pragma unroll
    for (int t = 0; t < 8; ++t) { brow[t] = BIGV; rightraw[t] = BIGV; rightW[t] = BIGV; }

    f32x4 bufA[16], bufB[16];

    auto load_diag = [&](int sp, f32x4* buf) {
        if (sp > 100) sp = 100;
        int len = diag_len(sp), i0 = diag_i0(sp), Cs = diag_Cs(sp);
        int pos = lane - i0;
        pos = pos < 0 ? 0 : pos;
        pos = pos > len - 1 ? len - 1 : pos;
        const float* srcb = Dp + Cs*64 + pos*4;
        int str = len * 4;
#pragma unroll
        for (int k = 0; k < 16; ++k)
            buf[k] = *(const f32x4*)(srcb + k*str);
    };

#define TILE_STEP(CUR, NXT, SVAL, DO_LOAD)                                    \
    {                                                                          \
        const int s_ = (SVAL);                                                 \
        if (DO_LOAD) {                                                         \
            load_diag(s_ + 1, NXT);                                            \
            __builtin_amdgcn_sched_barrier(0);                                 \
        }                                                                      \
        bool jz = (s_ == lane);            /* J == 0 */                        \
        float brnew = brow[7];                                                 \
        float upraw[8], upW[8];                                                \
        _Pragma("unroll")                                                      \
        for (int c = 0; c < 8; ++c) {                                          \
            upraw[c] = wave_shr1(brow[c], BIGV);                               \
            upW[c] = upraw[c] + WARP_PEN;                                      \
        }                                                                      \
        float corner = wave_shr1(brold, BIGV);                                 \
        if (jz) corner = (lane == 0) ? 0.f : BIGV;                             \
        float vr[8][8], vw[8][8];                                              \
        _Pragma("unroll")                                                      \
        for (int d = 0; d < 15; ++d) {                                         \
            _Pragma("unroll")                                                  \
            for (int r = 0; r < 8; ++r) {                                      \
                const int c = d - r;                                           \
                if (c < 0 || c > 7) continue;                                  \
                float uw = (r == 0) ? upW[c] : vw[r-1][c];                     \
                float lw = (c == 0) ? (jz ? BIGV : rightW[r]) : vw[r][c-1];    \
                float dg;                                                      \
                if (r == 0 && c == 0)      dg = corner;                        \
                else if (r == 0)           dg = upraw[c-1];                    \
                else if (c == 0)           dg = jz ? BIGV : rightraw[r-1];     \
                else                       dg = vr[r-1][c-1];                  \
                float v = fminf(fminf(uw, lw), dg) + CUR[r*2 + (c>>2)][c&3];   \
                vr[r][c] = v;                                                  \
                vw[r][c] = v + WARP_PEN;                                       \
            }                                                                  \
        }                                                                      \
        v00 = vr[0][0];                                                        \
        _Pragma("unroll")                                                      \
        for (int r = 0; r < 8; ++r) { rightraw[r] = vr[r][7]; rightW[r] = vw[r][7]; } \
        _Pragma("unroll")                                                      \
        for (int c = 0; c < 8; ++c) brow[c] = vr[7][c];                        \
        brold = brnew;                                                         \
    }

    load_diag(0, bufA);

    for (int sb = 0; sb < 100; sb += 2) {
        TILE_STEP(bufA, bufB, sb,     1)
        TILE_STEP(bufB, bufA, sb + 1, 1)
    }
    TILE_STEP(bufA, bufB, 100, 0)   // final tile-diagonal
#undef TILE_STEP

    // R[400][400] = tile(50,50) cell (0,0), computed at s=100 by lane 50
    if (lane == 50) atomicAdd(&acc[6 + (prob >> 3)], v00);
}

// ---------------- kernel 5: assemble outputs ----------------
__global__ void finalize(const float* __restrict__ acc,
                         const float* __restrict__ dur,
                         const float* __restrict__ pit,
                         float* __restrict__ out) {
    if (threadIdx.x != 0 || blockIdx.x != 0) return;
    float t[6] = {0.f, 0.f, 0.f, 0.f, 0.f, 0.f};
    for (int s = 0; s < 8; ++s)
        for (int c = 0; c < 6; ++c)
            t[c] += acc[SLOT_OFF + s*16 + c];
    float gen  = t[0] / 3200.f;
    float e2e  = t[1] / 3200.f;
    float fm   = 4.f * t[2] / 409600.f;
    float melv = 45.f * t[3] / 256000.f;
    float d    = dur[0];
    float p    = pit[0];
    float kl   = acc[6] / t[4];
    float klf  = acc[7] / t[5];
    out[0] = gen; out[1] = e2e; out[2] = fm; out[3] = melv;
    out[4] = d;   out[5] = p;   out[6] = kl; out[7] = klf;
    out[8] = gen + e2e + fm + melv + d + p + kl + klf;
}

// ---------------- launch ----------------
extern "C" void kernel_launch(void* const* d_in, const int* in_sizes, int n_in,
                              void* d_out, int out_size, void* d_ws, size_t ws_size,
                              hipStream_t stream) {
    const float* mel    = (const float*)d_in[0];
    const float* melh   = (const float*)d_in[1];
    const float* sg     = (const float*)d_in[2];
    const float* se     = (const float*)d_in[3];
    const float* fr     = (const float*)d_in[4];
    const float* ff     = (const float*)d_in[5];
    const float* dur    = (const float*)d_in[6];
    const float* pit    = (const float*)d_in[7];
    const float* z_p    = (const float*)d_in[8];
    const float* m_p    = (const float*)d_in[9];
    const float* logs_p = (const float*)d_in[10];
    const float* z_q    = (const float*)d_in[11];
    const float* m_q    = (const float*)d_in[12];
    const float* logs_q = (const float*)d_in[13];
    const int*   p_mask = (const int*)d_in[14];
    const int*   z_mask = (const int*)d_in[15];
    float* ws  = (float*)d_ws;
    float* out = (float*)d_out;

    hipMemsetAsync(ws, 0, 160 * sizeof(float), stream);
    colsum<<<B*7, 256, 0, stream>>>(logs_p, m_p, logs_q, m_q, ws);
    fused_kl_scalar<<<KLBLOCKS + SBLOCKS, 256, 0, stream>>>(
        z_p, m_p, logs_p, z_q, m_q, logs_q, p_mask, z_mask, ws,
        mel, melh, sg, se, fr, ff);
    dtw_diag<<<NPROB, 64, 0, stream>>>(ws + DMAT_OFF, ws);
    finalize<<<1, 64, 0, stream>>>(ws, dur, pit, out);
}